// Round 10
// baseline (6539.436 us; speedup 1.0000x reference)
//
#include <hip/hip_runtime.h>

#define DEV static __device__ __forceinline__

typedef _Float16 half8  __attribute__((ext_vector_type(8)));
typedef _Float16 half4v __attribute__((ext_vector_type(4)));
typedef float    floatx4 __attribute__((ext_vector_type(4)));
typedef unsigned int u32;
typedef unsigned long long u64;
typedef u32 u32x4 __attribute__((ext_vector_type(4)));

// Split scale: lo = f16((v - f16(v)) * 1024); combine = hi + lo/1024.
#define SPLIT_S 1024.0f
#define SPLIT_R (1.0f / 1024.0f)

// async global->LDS, 16B/lane: LDS dest wave-uniform base + lane*16.
DEV void gl_lds16(const _Float16* g, _Float16* l) {
  __builtin_amdgcn_global_load_lds(
      (const __attribute__((address_space(1))) u32*)g,
      (__attribute__((address_space(3))) u32*)l, 16, 0, 0);
}

// LLC-coherent (bypass L1/L2) 16B load/store; 16B dwordx4 is a single
// transaction -> tag in the same 16B implies payload validity.
DEV u32x4 llc_load16(u64 addr) {
  u32x4 r;
  asm volatile("global_load_dwordx4 %0, %1, off sc0 sc1"
               : "=v"(r) : "v"(addr));
  return r;
}
DEV void llc_store16(u64 addr, u32x4 v) {
  asm volatile("global_store_dwordx4 %0, %1, off sc0 sc1"
               :: "v"(addr), "v"(v) : "memory");
}

// Overflow-safe fast tanh: tanh(x) = sign(x) * (1 - 2/(1+e^{2|x|})).
DEV float fast_tanh(float x) {
  const float e = __expf(2.0f * fabsf(x));
  return copysignf(1.0f - 2.0f / (1.0f + e), x);
}

// ---------------------------------------------------------------------------
// h_pub tagged-packet layout (16B packets = {u32 d0,d1: 4 f16 halves; tag; tag}):
//   packet index (within parity) = part*4096 + c4*8 + row
//     part: 0=hi 1=lo; c4 = k/4 (512); row = batch (8)
//   byte addr = parity*131072 + idx*16.   h(tau): parity tau&1, tag == tau.
// Coalesced BOTH ways: consumer gather instr touches full 64B lines; producer
// owner lanes (8 rows x 16B) write full lines.
// Convert W_out->f16; parity0 = split(h0) tag 0; parity1 = invalid tags.
__global__ __launch_bounds__(256) void k_convert(
    const float* __restrict__ wout, const float* __restrict__ h0,
    _Float16* __restrict__ WoutF, char* __restrict__ hpub)
{
  const int NW4 = (2048 * 2048) / 4;
  for (int i = blockIdx.x * 256 + threadIdx.x; i < NW4; i += gridDim.x * 256) {
    const float4 v = ((const float4*)wout)[i];
    half4v o;
    o[0] = (_Float16)v.x; o[1] = (_Float16)v.y;
    o[2] = (_Float16)v.z; o[3] = (_Float16)v.w;
    ((half4v*)WoutF)[i] = o;
  }
  // 8192 packets per parity: id = part*4096 + c4*8 + row.
  for (int id = blockIdx.x * 256 + threadIdx.x; id < 8192; id += gridDim.x * 256) {
    const int part = id >> 12, c4 = (id >> 3) & 511, row = id & 7;
    union { _Float16 h[4]; u32 d[2]; } p;
#pragma unroll
    for (int j = 0; j < 4; ++j) {
      const float v = h0[row * 2048 + c4 * 4 + j];
      const _Float16 hh = (_Float16)v;
      p.h[j] = (part == 0) ? hh : (_Float16)((v - (float)hh) * SPLIT_S);
    }
    u32x4 pkt = { p.d[0], p.d[1], 0u, 0u };
    *(u32x4*)(hpub + (size_t)id * 16) = pkt;
    u32x4 inv = { 0u, 0u, 0xFFFFFFFFu, 0xFFFFFFFFu };
    *(u32x4*)(hpub + 131072 + (size_t)id * 16) = inv;
  }
}

// ---------------------------------------------------------------------------
// Split-f16 GEMM: C[m,n] = sum_k A[m,k]*B[n,k], A/B fp32 row-major (MxK, NxK).
// EPI 0: C = silu(v) fp32.  EPI 1: C[(t*8+b)*N+n] = v + bias[n] fp32.
template <int EPI>
__global__ __launch_bounds__(256) void k_gemm_split(
    const float* __restrict__ A, const float* __restrict__ B,
    float* __restrict__ C, const float* __restrict__ bias,
    int M, int N, int K)
{
  __shared__ _Float16 Ah[4096], Al[4096], Bh[4096], Bl[4096];
  const int tid  = threadIdx.x;
  const int lane = tid & 63, wave = tid >> 6;
  const int wm = wave >> 1, wn = wave & 1;
  const int tm = blockIdx.y * 128, tn = blockIdx.x * 128;
  const int lr = lane & 15, lk = lane >> 4;

  floatx4 acch[4][4] = {};
  floatx4 accl[4][4] = {};

  for (int k0 = 0; k0 < K; k0 += 32) {
    float4 av[4], bv[4];
#pragma unroll
    for (int q = 0; q < 4; ++q) {
      const int c = tid + q * 256;           // chunk 0..1023 (float4 units)
      const int rr = c >> 3, cc = (c & 7) * 4;
      av[q] = *(const float4*)(A + (size_t)(tm + rr) * K + k0 + cc);
      bv[q] = *(const float4*)(B + (size_t)(tn + rr) * K + k0 + cc);
    }
    __syncthreads();   // previous iteration's frag reads complete
#pragma unroll
    for (int q = 0; q < 4; ++q) {
      const int c = tid + q * 256;
      const int rr = c >> 3, cc = (c & 7) * 4;
      half4v ah, al, bh, bl;
#pragma unroll
      for (int j = 0; j < 4; ++j) {
        const float xa = av[q][j], xb = bv[q][j];
        const _Float16 ha = (_Float16)xa, hb = (_Float16)xb;
        ah[j] = ha; al[j] = (_Float16)((xa - (float)ha) * SPLIT_S);
        bh[j] = hb; bl[j] = (_Float16)((xb - (float)hb) * SPLIT_S);
      }
      *(half4v*)(Ah + rr * 32 + cc) = ah;
      *(half4v*)(Al + rr * 32 + cc) = al;
      *(half4v*)(Bh + rr * 32 + cc) = bh;
      *(half4v*)(Bl + rr * 32 + cc) = bl;
    }
    __syncthreads();

    half8 fah[4], fal[4], fbh[4], fbl[4];
#pragma unroll
    for (int mi = 0; mi < 4; ++mi) {
      const int off = (wm * 64 + mi * 16 + lr) * 32 + lk * 8;
      fah[mi] = *(const half8*)(Ah + off);
      fal[mi] = *(const half8*)(Al + off);
    }
#pragma unroll
    for (int ni = 0; ni < 4; ++ni) {
      const int off = (wn * 64 + ni * 16 + lr) * 32 + lk * 8;
      fbh[ni] = *(const half8*)(Bh + off);
      fbl[ni] = *(const half8*)(Bl + off);
    }
#pragma unroll
    for (int mi = 0; mi < 4; ++mi)
#pragma unroll
      for (int ni = 0; ni < 4; ++ni) {
        acch[mi][ni] = __builtin_amdgcn_mfma_f32_16x16x32_f16(fah[mi], fbh[ni], acch[mi][ni], 0, 0, 0);
        accl[mi][ni] = __builtin_amdgcn_mfma_f32_16x16x32_f16(
            fah[mi], fbl[ni],
            __builtin_amdgcn_mfma_f32_16x16x32_f16(fal[mi], fbh[ni], accl[mi][ni], 0, 0, 0),
            0, 0, 0);
      }
  }

#pragma unroll
  for (int mi = 0; mi < 4; ++mi)
#pragma unroll
    for (int ni = 0; ni < 4; ++ni) {
      const int gcol = tn + wn * 64 + ni * 16 + lr;
#pragma unroll
      for (int r = 0; r < 4; ++r) {
        const int grow = tm + wm * 64 + mi * 16 + lk * 4 + r;
        const float v = acch[mi][ni][r] + accl[mi][ni][r] * SPLIT_R;
        if (EPI == 0) {
          C[(size_t)grow * N + gcol] = v / (1.0f + __expf(-v));
        } else {
          const int tt = grow & 1023, bb = grow >> 10;
          C[(size_t)(tt * 8 + bb) * N + gcol] = v + bias[gcol];
        }
      }
    }
}

// ---------------------------------------------------------------------------
// Plain-f16 GEMM for y = (outs/8) . Wout^T, epilogue *8.
__global__ __launch_bounds__(256) void k_gemm_out(
    const _Float16* __restrict__ A, const _Float16* __restrict__ B,
    float* __restrict__ C, int M, int N, int K)
{
  __shared__ _Float16 As[4096];
  __shared__ _Float16 Bs[4096];
  const int tid  = threadIdx.x;
  const int lane = tid & 63, wave = tid >> 6;
  const int wm = wave >> 1, wn = wave & 1;
  const int tm = blockIdx.y * 128, tn = blockIdx.x * 128;
  const int lr = lane & 15, lk = lane >> 4;
  const int r0 = tid >> 2;
  const int c0 = (tid & 3) * 8;

  floatx4 acc[4][4] = {};

  for (int k0 = 0; k0 < K; k0 += 32) {
#pragma unroll
    for (int c = 0; c < 2; ++c) {
      const int row = c * 64 + r0;
      gl_lds16(A + (size_t)(tm + row) * K + k0 + c0, As + c * 2048 + wave * 512);
      gl_lds16(B + (size_t)(tn + row) * K + k0 + c0, Bs + c * 2048 + wave * 512);
    }
    __syncthreads();

    half8 af[4], bf[4];
#pragma unroll
    for (int mi = 0; mi < 4; ++mi)
      af[mi] = *(const half8*)(As + (wm * 64 + mi * 16 + lr) * 32 + lk * 8);
#pragma unroll
    for (int ni = 0; ni < 4; ++ni)
      bf[ni] = *(const half8*)(Bs + (wn * 64 + ni * 16 + lr) * 32 + lk * 8);
#pragma unroll
    for (int mi = 0; mi < 4; ++mi)
#pragma unroll
      for (int ni = 0; ni < 4; ++ni)
        acc[mi][ni] = __builtin_amdgcn_mfma_f32_16x16x32_f16(af[mi], bf[ni], acc[mi][ni], 0, 0, 0);
    __syncthreads();
  }

#pragma unroll
  for (int mi = 0; mi < 4; ++mi)
#pragma unroll
    for (int ni = 0; ni < 4; ++ni) {
      const int gcol = tn + wn * 64 + ni * 16 + lr;
#pragma unroll
      for (int r = 0; r < 4; ++r) {
        const int grow = tm + wm * 64 + mi * 16 + lk * 4 + r;
        C[(size_t)grow * N + gcol] = acc[mi][ni][r] * 8.0f;
      }
    }
}

// ---------------------------------------------------------------------------
// Persistent recurrence, split-f16, COALESCED SEQLOCK, r5 control structure:
// sequential part processing (max 32 packets live -> no spill), per-lane
// while(m) retry, parity-double-buffered red, ONE barrier/step, no flags.
// 128 WGs x 256 thr (1 WG/CU).
__global__ __launch_bounds__(256, 1) void k_recur(
    const float* __restrict__ Wh, const float* __restrict__ wxp,
    const float* __restrict__ h0p, const float* __restrict__ lalpha,
    _Float16* __restrict__ outs, char* __restrict__ h_pub)
{
  __shared__ float red[2 * 256 * 4];   // 8KB, parity-double-buffered
  const int tid = threadIdx.x;
  const int lane = tid & 63, wave = tid >> 6;
  const int g = blockIdx.x;
  const int e0 = g * 16;
  const int lr = lane & 15, lk = lane >> 4;
  const int lrc = lr & 7;   // lanes lr>=8 duplicate row lr-8 (dead B cols)
  const float alpha = __expf(lalpha[0]);

  // Preload + split W_h fragments (fp32 global -> hi/lo f16 regs), once.
  half8 afh[16], afl[16];
#pragma unroll
  for (int ks = 0; ks < 16; ++ks) {
    const float* wp = Wh + (size_t)(e0 + lr) * 2048 + wave * 512 + ks * 32 + lk * 8;
    const float4 f0 = *(const float4*)wp;
    const float4 f1 = *(const float4*)(wp + 4);
    half8 h, l;
#pragma unroll
    for (int j = 0; j < 4; ++j) {
      const float a0 = ((const float*)&f0)[j], a1 = ((const float*)&f1)[j];
      const _Float16 h0_ = (_Float16)a0;
      const _Float16 h1_ = (_Float16)a1;
      h[j]     = h0_; l[j]     = (_Float16)((a0 - (float)h0_) * SPLIT_S);
      h[j + 4] = h1_; l[j + 4] = (_Float16)((a1 - (float)h1_) * SPLIT_S);
    }
    afh[ks] = h; afl[ks] = l;
  }

  const bool owner = (tid < 64) && (lr < 8);  // owns (batch lr, cols e0+lk*4..+4)
  float hr0 = 0.f, hr1 = 0.f, hr2 = 0.f, hr3 = 0.f;
  if (owner) {
    const float4 hv = *(const float4*)(h0p + (size_t)lr * 2048 + e0 + lk * 4);
    hr0 = hv.x; hr1 = hv.y; hr2 = hv.z; hr3 = hv.w;
  }

  const u64 hbase = (u64)h_pub;
  // Per-lane gather base within a part (coalesced, fragment-exact):
  //   byte = wave*16384 + lk*256 + lrc*16  (+ ks*1024 + j*128)
  const u64 gb_off = (u64)(wave * 16384 + lk * 256 + lrc * 16);
  // Producer packet byte (within part): g*512 + lk*128 + lr*16.
  const u64 pub_off = (u64)(g * 512 + lk * 128 + lr * 16);

  for (int t = 0; t < 1024; ++t) {
    // Prefetch wx_t (plain cached; consumed in tail).
    float4 wv = {0.f, 0.f, 0.f, 0.f};
    if (owner) wv = *(const float4*)(wxp + (size_t)(t * 8 + lr) * 2048 + e0 + lk * 4);

    const u64 pb = hbase + (u64)(t & 1) * 131072 + gb_off;
    const u32 tag = (u32)t;
    floatx4 pacc[4] = {};
    floatx4 lacc[4] = {};
    u32x4 pk[32];   // only 32 packets live at any time (r5-proven budget)

#pragma unroll
    for (int part = 0; part < 2; ++part) {
      const u64 pp = pb + (u64)part * 65536;
      // Issue all 32 packet loads of this part (coalesced full lines).
#pragma unroll
      for (int ks = 0; ks < 16; ++ks) {
        pk[2 * ks]     = llc_load16(pp + (u64)ks * 1024);
        pk[2 * ks + 1] = llc_load16(pp + (u64)ks * 1024 + 128);
      }
      asm volatile("s_waitcnt vmcnt(0)" ::: "memory");
      __builtin_amdgcn_sched_barrier(0);
      u32 m = 0;
#pragma unroll
      for (int i = 0; i < 32; ++i) m |= (pk[i][2] != tag) ? (1u << i) : 0u;
      while (m) {   // per-lane spin; re-issue only stale packets (coalesced)
#pragma unroll
        for (int i = 0; i < 32; ++i)
          if (m & (1u << i))
            pk[i] = llc_load16(pp + (u64)(i >> 1) * 1024 + (u64)(i & 1) * 128);
        asm volatile("s_waitcnt vmcnt(0)" ::: "memory");
        __builtin_amdgcn_sched_barrier(0);
#pragma unroll
        for (int i = 0; i < 32; ++i)
          if ((m & (1u << i)) && pk[i][2] == tag) m &= ~(1u << i);
      }
      // MFMAs for this part.
      if (part == 0) {
#pragma unroll
        for (int ks = 0; ks < 16; ++ks) {
          u32x4 f = { pk[2 * ks][0], pk[2 * ks][1], pk[2 * ks + 1][0], pk[2 * ks + 1][1] };
          const half8 bh = __builtin_bit_cast(half8, f);
          pacc[ks & 3] = __builtin_amdgcn_mfma_f32_16x16x32_f16(afh[ks], bh, pacc[ks & 3], 0, 0, 0);
          lacc[ks & 3] = __builtin_amdgcn_mfma_f32_16x16x32_f16(afl[ks], bh, lacc[ks & 3], 0, 0, 0);
        }
      } else {
#pragma unroll
        for (int ks = 0; ks < 16; ++ks) {
          u32x4 f = { pk[2 * ks][0], pk[2 * ks][1], pk[2 * ks + 1][0], pk[2 * ks + 1][1] };
          const half8 bl = __builtin_bit_cast(half8, f);
          lacc[ks & 3] = __builtin_amdgcn_mfma_f32_16x16x32_f16(afh[ks], bl, lacc[ks & 3], 0, 0, 0);
        }
      }
    }

    const floatx4 pt = (pacc[0] + pacc[1] + pacc[2] + pacc[3]) +
                       (lacc[0] + lacc[1] + lacc[2] + lacc[3]) * SPLIT_R;
    *(floatx4*)&red[(((t & 1) * 256) + wave * 64 + lane) * 4] = pt;
    __syncthreads();   // the only barrier per step (red is parity-dbuf'd)

    if (tid < 64) {
      const floatx4* R = (const floatx4*)red + (t & 1) * 256;
      const floatx4 s = R[lane] + R[64 + lane] + R[128 + lane] + R[192 + lane];
      union { _Float16 h[4]; u32 d[2]; u64 u; } hv, lv, ov;
      if (owner) {
        hr0 += alpha * fast_tanh(s[0] + wv.x);
        hr1 += alpha * fast_tanh(s[1] + wv.y);
        hr2 += alpha * fast_tanh(s[2] + wv.z);
        hr3 += alpha * fast_tanh(s[3] + wv.w);
        hv.h[0] = (_Float16)hr0; hv.h[1] = (_Float16)hr1;
        hv.h[2] = (_Float16)hr2; hv.h[3] = (_Float16)hr3;
        lv.h[0] = (_Float16)((hr0 - (float)hv.h[0]) * SPLIT_S);
        lv.h[1] = (_Float16)((hr1 - (float)hv.h[1]) * SPLIT_S);
        lv.h[2] = (_Float16)((hr2 - (float)hv.h[2]) * SPLIT_S);
        lv.h[3] = (_Float16)((hr3 - (float)hv.h[3]) * SPLIT_S);
        const u32 ntag = (u32)(t + 1);
        const u64 dst = hbase + (u64)((t + 1) & 1) * 131072 + pub_off;
        u32x4 hpk = { hv.d[0], hv.d[1], ntag, ntag };
        u32x4 lpk = { lv.d[0], lv.d[1], ntag, ntag };
        llc_store16(dst,         hpk);   // fire-and-forget; consumers spin on tag
        llc_store16(dst + 65536, lpk);
        // outs consumed only by the next dispatch -> off the critical path.
        ov.h[0] = (_Float16)((hr0 * hr0 / (1.f + __expf(-hr0))) * 0.125f);
        ov.h[1] = (_Float16)((hr1 * hr1 / (1.f + __expf(-hr1))) * 0.125f);
        ov.h[2] = (_Float16)((hr2 * hr2 / (1.f + __expf(-hr2))) * 0.125f);
        ov.h[3] = (_Float16)((hr3 * hr3 / (1.f + __expf(-hr3))) * 0.125f);
        *(u64*)(outs + (size_t)(lr * 1024 + t) * 2048 + e0 + lk * 4) = ov.u;
      }
    }
    // No further sync: publish(t+1) happens only after this WG fully gathered
    // t, and any WG's publish(t+2) requires ALL WGs to have gathered t ->
    // no live reader of tag t exists when its slot is overwritten (induction,
    // proven in r5). red parity gives wave0 a full step of slack.
  }
}

// ---------------------------------------------------------------------------
extern "C" void kernel_launch(void* const* d_in, const int* in_sizes, int n_in,
                              void* d_out, int out_size, void* d_ws, size_t ws_size,
                              hipStream_t stream)
{
  (void)in_sizes; (void)n_in; (void)out_size; (void)ws_size;
  const float* x    = (const float*)d_in[0];
  const float* h0   = (const float*)d_in[1];
  const float* Win  = (const float*)d_in[2];
  const float* Wx   = (const float*)d_in[3];
  const float* Wh   = (const float*)d_in[4];
  const float* bias = (const float*)d_in[5];
  const float* lal  = (const float*)d_in[6];
  const float* Wout = (const float*)d_in[7];

  char* ws = (char*)d_ws;
  float*    U     = (float*)(ws);                    // 67,108,864 B (fp32 u)
  _Float16* OUTS  = (_Float16*)(ws);                 // aliases U (U dead after GEMM2)
  _Float16* WoutF = (_Float16*)(ws + 67108864);      //  8,388,608 B
  char*     hpub  = ws + 75497472;                   //    262,144 B tagged packets
  float*    wxbuf = (float*)d_out;                   // wx staged in d_out

  const dim3 gg(16, 64);  // N/128, M/128

  k_convert<<<512, 256, 0, stream>>>(Wout, h0, WoutF, hpub);
  // u = silu(x . W_in^T)  (split-f16, fp32 out)
  k_gemm_split<0><<<gg, 256, 0, stream>>>(x, Win, U, nullptr, 8192, 2048, 2048);
  // wx[t][b][:] = u . W_x^T + b  (split-f16, fp32 out in d_out)
  k_gemm_split<1><<<gg, 256, 0, stream>>>(U, Wx, wxbuf, bias, 8192, 2048, 2048);
  // sequential scan; writes outs/8 (f16) over the dead U region
  k_recur<<<128, 256, 0, stream>>>(Wh, wxbuf, h0, lal, OUTS, hpub);
  // y = outs . W_out^T  (epilogue *8), overwrites d_out
  k_gemm_out<<<gg, 256, 0, stream>>>(OUTS, WoutF, (float*)d_out, 8192, 2048, 2048);
}

// Round 11
// 6177.735 us; speedup vs baseline: 1.0585x; 1.0585x over previous
//
#include <hip/hip_runtime.h>

#define DEV static __device__ __forceinline__

typedef _Float16 half8  __attribute__((ext_vector_type(8)));
typedef _Float16 half4v __attribute__((ext_vector_type(4)));
typedef float    floatx4 __attribute__((ext_vector_type(4)));
typedef unsigned int u32;
typedef unsigned long long u64;
typedef u32 u32x4 __attribute__((ext_vector_type(4)));

// Split scale: lo = f16((v - f16(v)) * 1024); combine = hi + lo/1024.
#define SPLIT_S 1024.0f
#define SPLIT_R (1.0f / 1024.0f)

// async global->LDS, 16B/lane: LDS dest wave-uniform base + lane*16.
DEV void gl_lds16(const _Float16* g, _Float16* l) {
  __builtin_amdgcn_global_load_lds(
      (const __attribute__((address_space(1))) u32*)g,
      (__attribute__((address_space(3))) u32*)l, 16, 0, 0);
}

// LLC-coherent (bypass L1/L2) 16B load. Freshness via sc0+sc1.
DEV u32x4 llc_load16(u64 addr) {
  u32x4 r;
  asm volatile("global_load_dwordx4 %0, %1, off sc0 sc1"
               : "=v"(r) : "v"(addr));
  return r;
}
// No-return atomic swaps: execute & complete AT the MALL -> cheap vmcnt ack
// (no HBM write-through wait on the critical path). Device-scope by default.
DEV void mall_swap8(u64 addr, u64 v) {
  asm volatile("global_atomic_swap_x2 %0, %1, off"
               :: "v"(addr), "v"(v) : "memory");
}
DEV void mall_swap4(u64 addr, int v) {
  asm volatile("global_atomic_swap %0, %1, off"
               :: "v"(addr), "v"(v) : "memory");
}

// Overflow-safe fast tanh: tanh(x) = sign(x) * (1 - 2/(1+e^{2|x|})).
DEV float fast_tanh(float x) {
  const float e = __expf(2.0f * fabsf(x));
  return copysignf(1.0f - 2.0f / (1.0f + e), x);
}

// ---------------------------------------------------------------------------
// h_pub CHUNK-TRANSPOSED layout (bytes):
//   [parity(2) stride 65536][part(2) stride 32768][kchunk(256) stride 128][row(8) stride 16]
// 16B unit = h[row][kchunk*8 .. +8) as f16. Consumer gather is coalesced AND
// fragment-exact (no LDS staging, no shuffles).
// Convert W_out->f16; init h_pub parity0 = split(h0); zero flags (128).
__global__ __launch_bounds__(256) void k_convert(
    const float* __restrict__ wout, const float* __restrict__ h0,
    _Float16* __restrict__ WoutF, char* __restrict__ hpub,
    int* __restrict__ flags)
{
  if (blockIdx.x == 0 && threadIdx.x < 128) flags[threadIdx.x] = 0;
  const int NW4 = (2048 * 2048) / 4;
  for (int i = blockIdx.x * 256 + threadIdx.x; i < NW4; i += gridDim.x * 256) {
    const float4 v = ((const float4*)wout)[i];
    half4v o;
    o[0] = (_Float16)v.x; o[1] = (_Float16)v.y;
    o[2] = (_Float16)v.z; o[3] = (_Float16)v.w;
    ((half4v*)WoutF)[i] = o;
  }
  // 2048 cells: chunk c = id>>3 (256), row b = id&7.
  for (int id = blockIdx.x * 256 + threadIdx.x; id < 2048; id += gridDim.x * 256) {
    const int c = id >> 3, b = id & 7;
    union { _Float16 h[8]; u32x4 v; } hi, lo;
#pragma unroll
    for (int j = 0; j < 8; ++j) {
      const float v = h0[b * 2048 + c * 8 + j];
      const _Float16 h = (_Float16)v;
      hi.h[j] = h;
      lo.h[j] = (_Float16)((v - (float)h) * SPLIT_S);
    }
    *(u32x4*)(hpub + c * 128 + b * 16)         = hi.v;
    *(u32x4*)(hpub + 32768 + c * 128 + b * 16) = lo.v;
  }
}

// ---------------------------------------------------------------------------
// Split-f16 GEMM: C[m,n] = sum_k A[m,k]*B[n,k], A/B fp32 row-major (MxK, NxK).
// EPI 0: C = silu(v) fp32.  EPI 1: C[(t*8+b)*N+n] = v + bias[n] fp32.
template <int EPI>
__global__ __launch_bounds__(256) void k_gemm_split(
    const float* __restrict__ A, const float* __restrict__ B,
    float* __restrict__ C, const float* __restrict__ bias,
    int M, int N, int K)
{
  __shared__ _Float16 Ah[4096], Al[4096], Bh[4096], Bl[4096];
  const int tid  = threadIdx.x;
  const int lane = tid & 63, wave = tid >> 6;
  const int wm = wave >> 1, wn = wave & 1;
  const int tm = blockIdx.y * 128, tn = blockIdx.x * 128;
  const int lr = lane & 15, lk = lane >> 4;

  floatx4 acch[4][4] = {};
  floatx4 accl[4][4] = {};

  for (int k0 = 0; k0 < K; k0 += 32) {
    float4 av[4], bv[4];
#pragma unroll
    for (int q = 0; q < 4; ++q) {
      const int c = tid + q * 256;           // chunk 0..1023 (float4 units)
      const int rr = c >> 3, cc = (c & 7) * 4;
      av[q] = *(const float4*)(A + (size_t)(tm + rr) * K + k0 + cc);
      bv[q] = *(const float4*)(B + (size_t)(tn + rr) * K + k0 + cc);
    }
    __syncthreads();   // previous iteration's frag reads complete
#pragma unroll
    for (int q = 0; q < 4; ++q) {
      const int c = tid + q * 256;
      const int rr = c >> 3, cc = (c & 7) * 4;
      half4v ah, al, bh, bl;
#pragma unroll
      for (int j = 0; j < 4; ++j) {
        const float xa = av[q][j], xb = bv[q][j];
        const _Float16 ha = (_Float16)xa, hb = (_Float16)xb;
        ah[j] = ha; al[j] = (_Float16)((xa - (float)ha) * SPLIT_S);
        bh[j] = hb; bl[j] = (_Float16)((xb - (float)hb) * SPLIT_S);
      }
      *(half4v*)(Ah + rr * 32 + cc) = ah;
      *(half4v*)(Al + rr * 32 + cc) = al;
      *(half4v*)(Bh + rr * 32 + cc) = bh;
      *(half4v*)(Bl + rr * 32 + cc) = bl;
    }
    __syncthreads();

    half8 fah[4], fal[4], fbh[4], fbl[4];
#pragma unroll
    for (int mi = 0; mi < 4; ++mi) {
      const int off = (wm * 64 + mi * 16 + lr) * 32 + lk * 8;
      fah[mi] = *(const half8*)(Ah + off);
      fal[mi] = *(const half8*)(Al + off);
    }
#pragma unroll
    for (int ni = 0; ni < 4; ++ni) {
      const int off = (wn * 64 + ni * 16 + lr) * 32 + lk * 8;
      fbh[ni] = *(const half8*)(Bh + off);
      fbl[ni] = *(const half8*)(Bl + off);
    }
#pragma unroll
    for (int mi = 0; mi < 4; ++mi)
#pragma unroll
      for (int ni = 0; ni < 4; ++ni) {
        acch[mi][ni] = __builtin_amdgcn_mfma_f32_16x16x32_f16(fah[mi], fbh[ni], acch[mi][ni], 0, 0, 0);
        accl[mi][ni] = __builtin_amdgcn_mfma_f32_16x16x32_f16(
            fah[mi], fbl[ni],
            __builtin_amdgcn_mfma_f32_16x16x32_f16(fal[mi], fbh[ni], accl[mi][ni], 0, 0, 0),
            0, 0, 0);
      }
  }

#pragma unroll
  for (int mi = 0; mi < 4; ++mi)
#pragma unroll
    for (int ni = 0; ni < 4; ++ni) {
      const int gcol = tn + wn * 64 + ni * 16 + lr;
#pragma unroll
      for (int r = 0; r < 4; ++r) {
        const int grow = tm + wm * 64 + mi * 16 + lk * 4 + r;
        const float v = acch[mi][ni][r] + accl[mi][ni][r] * SPLIT_R;
        if (EPI == 0) {
          C[(size_t)grow * N + gcol] = v / (1.0f + __expf(-v));
        } else {
          const int tt = grow & 1023, bb = grow >> 10;
          C[(size_t)(tt * 8 + bb) * N + gcol] = v + bias[gcol];
        }
      }
    }
}

// ---------------------------------------------------------------------------
// Plain-f16 GEMM for y = (outs/8) . Wout^T, epilogue *8.
__global__ __launch_bounds__(256) void k_gemm_out(
    const _Float16* __restrict__ A, const _Float16* __restrict__ B,
    float* __restrict__ C, int M, int N, int K)
{
  __shared__ _Float16 As[4096];
  __shared__ _Float16 Bs[4096];
  const int tid  = threadIdx.x;
  const int lane = tid & 63, wave = tid >> 6;
  const int wm = wave >> 1, wn = wave & 1;
  const int tm = blockIdx.y * 128, tn = blockIdx.x * 128;
  const int lr = lane & 15, lk = lane >> 4;
  const int r0 = tid >> 2;
  const int c0 = (tid & 3) * 8;

  floatx4 acc[4][4] = {};

  for (int k0 = 0; k0 < K; k0 += 32) {
#pragma unroll
    for (int c = 0; c < 2; ++c) {
      const int row = c * 64 + r0;
      gl_lds16(A + (size_t)(tm + row) * K + k0 + c0, As + c * 2048 + wave * 512);
      gl_lds16(B + (size_t)(tn + row) * K + k0 + c0, Bs + c * 2048 + wave * 512);
    }
    __syncthreads();

    half8 af[4], bf[4];
#pragma unroll
    for (int mi = 0; mi < 4; ++mi)
      af[mi] = *(const half8*)(As + (wm * 64 + mi * 16 + lr) * 32 + lk * 8);
#pragma unroll
    for (int ni = 0; ni < 4; ++ni)
      bf[ni] = *(const half8*)(Bs + (wn * 64 + ni * 16 + lr) * 32 + lk * 8);
#pragma unroll
    for (int mi = 0; mi < 4; ++mi)
#pragma unroll
      for (int ni = 0; ni < 4; ++ni)
        acc[mi][ni] = __builtin_amdgcn_mfma_f32_16x16x32_f16(af[mi], bf[ni], acc[mi][ni], 0, 0, 0);
    __syncthreads();
  }

#pragma unroll
  for (int mi = 0; mi < 4; ++mi)
#pragma unroll
    for (int ni = 0; ni < 4; ++ni) {
      const int gcol = tn + wn * 64 + ni * 16 + lr;
#pragma unroll
      for (int r = 0; r < 4; ++r) {
        const int grow = tm + wm * 64 + mi * 16 + lk * 4 + r;
        C[(size_t)grow * N + gcol] = acc[mi][ni][r] * 8.0f;
      }
    }
}

// ---------------------------------------------------------------------------
// Persistent recurrence, split-f16. r7 flag protocol with:
//   (1) MALL-atomic publish (h + flag via no-return swaps -> cheap ack)
//   (2) per-wave independent polling, NO barrier A -> waves 1-3 gather+MFMA
//       while wave0 finishes its tail (3/4 of compute off the critical path)
//   (3) parity-double-buffered red; barrier C is the only barrier per step.
// 128 WGs x 256 thr (1 WG/CU). Correctness: flag[g]=t implies WG g's wave0
// completed step t-1 incl. barrier C, so no wave anywhere still reads h(t-1)
// when h(t+1) overwrites that parity slot (same induction as r7).
__global__ __launch_bounds__(256, 1) void k_recur(
    const float* __restrict__ Wh, const float* __restrict__ wxp,
    const float* __restrict__ h0p, const float* __restrict__ lalpha,
    _Float16* __restrict__ outs, char* __restrict__ h_pub, int* flags)
{
  __shared__ float red[2 * 256 * 4];   // 8KB, parity-double-buffered
  const int tid = threadIdx.x;
  const int lane = tid & 63, wave = tid >> 6;
  const int g = blockIdx.x;
  const int e0 = g * 16;
  const int lr = lane & 15, lk = lane >> 4;
  const int lrc = lr & 7;   // lanes lr>=8 duplicate row lr-8 (dead B cols)
  const float alpha = __expf(lalpha[0]);

  // Preload + split W_h fragments (fp32 global -> hi/lo f16 regs), once.
  half8 afh[16], afl[16];
#pragma unroll
  for (int ks = 0; ks < 16; ++ks) {
    const float* wp = Wh + (size_t)(e0 + lr) * 2048 + wave * 512 + ks * 32 + lk * 8;
    const float4 f0 = *(const float4*)wp;
    const float4 f1 = *(const float4*)(wp + 4);
    half8 h, l;
#pragma unroll
    for (int j = 0; j < 4; ++j) {
      const float a0 = ((const float*)&f0)[j], a1 = ((const float*)&f1)[j];
      const _Float16 h0_ = (_Float16)a0;
      const _Float16 h1_ = (_Float16)a1;
      h[j]     = h0_; l[j]     = (_Float16)((a0 - (float)h0_) * SPLIT_S);
      h[j + 4] = h1_; l[j + 4] = (_Float16)((a1 - (float)h1_) * SPLIT_S);
    }
    afh[ks] = h; afl[ks] = l;
  }

  const bool owner = (tid < 64) && (lr < 8);  // owns (batch lr, cols e0+lk*4..+4)
  float hr0 = 0.f, hr1 = 0.f, hr2 = 0.f, hr3 = 0.f;
  if (owner) {
    const float4 hv = *(const float4*)(h0p + (size_t)lr * 2048 + e0 + lk * 4);
    hr0 = hv.x; hr1 = hv.y; hr2 = hv.z; hr3 = hv.w;
  }

  const u64 hbase = (u64)h_pub;
  const u64 flag_base = (u64)flags;
  // Per-lane gather base: chunk (wave*64 + ks*4 + lk), row lrc.
  const u64 gb_off = (u64)((wave * 64 + lk) * 128 + lrc * 16);

  for (int t = 0; t < 1024; ++t) {
    // Prefetch wx_t (plain cached; consumed in tail, hidden under poll+gather).
    float4 wv = {0.f, 0.f, 0.f, 0.f};
    if (owner) wv = *(const float4*)(wxp + (size_t)(t * 8 + lr) * 2048 + e0 + lk * 4);

    // Poll: EVERY wave independently; lane watches flags[2*lane], flags[2*lane+1].
    if (t > 0) {
      const u64* fp = (const u64*)flags + lane;
      for (;;) {
        const u64 fv = __hip_atomic_load(fp, __ATOMIC_RELAXED, __HIP_MEMORY_SCOPE_AGENT);
        if (__all(((int)fv >= t) && ((int)(fv >> 32) >= t))) break;
        __builtin_amdgcn_s_sleep(1);
      }
    }
    // No barrier: each wave proceeds to gather as soon as ITS poll passes.

    // ---- register-direct gather: hi then lo, all 32 loads in flight ----
    const u64 pb = hbase + (u64)(t & 1) * 65536 + gb_off;
    u32x4 sh[16], sl[16];
#pragma unroll
    for (int ks = 0; ks < 16; ++ks) sh[ks] = llc_load16(pb + (u64)ks * 512);
#pragma unroll
    for (int ks = 0; ks < 16; ++ks) sl[ks] = llc_load16(pb + 32768 + (u64)ks * 512);
    asm volatile("s_waitcnt vmcnt(16)" ::: "memory");   // hi complete
    __builtin_amdgcn_sched_barrier(0);

    // ---- hi MFMAs: ph += Ah.Bh ; pl += Al.Bh (lo loads still in flight) ----
    floatx4 ph[4] = {};
    floatx4 pl[4] = {};
#pragma unroll
    for (int ks = 0; ks < 16; ++ks) {
      const half8 bh = __builtin_bit_cast(half8, sh[ks]);
      ph[ks & 3] = __builtin_amdgcn_mfma_f32_16x16x32_f16(afh[ks], bh, ph[ks & 3], 0, 0, 0);
      pl[ks & 3] = __builtin_amdgcn_mfma_f32_16x16x32_f16(afl[ks], bh, pl[ks & 3], 0, 0, 0);
    }
    asm volatile("s_waitcnt vmcnt(0)" ::: "memory");    // lo complete
    __builtin_amdgcn_sched_barrier(0);

    // ---- lo MFMAs: pl += Ah.Bl ----
#pragma unroll
    for (int ks = 0; ks < 16; ++ks) {
      const half8 bl = __builtin_bit_cast(half8, sl[ks]);
      pl[ks & 3] = __builtin_amdgcn_mfma_f32_16x16x32_f16(afh[ks], bl, pl[ks & 3], 0, 0, 0);
    }
    const floatx4 pt = (ph[0] + ph[1] + ph[2] + ph[3]) +
                       (pl[0] + pl[1] + pl[2] + pl[3]) * SPLIT_R;
    *(floatx4*)&red[(((t & 1) * 256) + wave * 64 + lane) * 4] = pt;
    __syncthreads();   // C — the only barrier per step

    if (tid < 64) {
      const floatx4* R = (const floatx4*)red + (t & 1) * 256;
      const floatx4 s = R[lane] + R[64 + lane] + R[128 + lane] + R[192 + lane];
      union { _Float16 h[4]; u64 u; } hv, lv, ov;
      if (owner) {
        hr0 += alpha * fast_tanh(s[0] + wv.x);
        hr1 += alpha * fast_tanh(s[1] + wv.y);
        hr2 += alpha * fast_tanh(s[2] + wv.z);
        hr3 += alpha * fast_tanh(s[3] + wv.w);
        hv.h[0] = (_Float16)hr0; hv.h[1] = (_Float16)hr1;
        hv.h[2] = (_Float16)hr2; hv.h[3] = (_Float16)hr3;
        lv.h[0] = (_Float16)((hr0 - (float)hv.h[0]) * SPLIT_S);
        lv.h[1] = (_Float16)((hr1 - (float)hv.h[1]) * SPLIT_S);
        lv.h[2] = (_Float16)((hr2 - (float)hv.h[2]) * SPLIT_S);
        lv.h[3] = (_Float16)((hr3 - (float)hv.h[3]) * SPLIT_S);
        // MALL-atomic publish: chunk 2g+(lk>>1), row lr, byte-half (lk&1).
        const u64 dst = hbase + (u64)((t + 1) & 1) * 65536 +
                        (u64)((2 * g + (lk >> 1)) * 128 + lr * 16 + (lk & 1) * 8);
        mall_swap8(dst,         hv.u);   // hi
        mall_swap8(dst + 32768, lv.u);   // lo
      }
      // Ack at MALL (cheap — atomics complete at the coherence point),
      // then publish the flag atomically.
      asm volatile("s_waitcnt vmcnt(0)" ::: "memory");
      if (lane == 0) mall_swap4(flag_base + (u64)g * 4, t + 1);
      if (owner) {
        // outs consumed only by the next dispatch -> off the critical path.
        ov.h[0] = (_Float16)((hr0 * hr0 / (1.f + __expf(-hr0))) * 0.125f);
        ov.h[1] = (_Float16)((hr1 * hr1 / (1.f + __expf(-hr1))) * 0.125f);
        ov.h[2] = (_Float16)((hr2 * hr2 / (1.f + __expf(-hr2))) * 0.125f);
        ov.h[3] = (_Float16)((hr3 * hr3 / (1.f + __expf(-hr3))) * 0.125f);
        *(u64*)(outs + (size_t)(lr * 1024 + t) * 2048 + e0 + lk * 4) = ov.u;
      }
    }
    // Parity-red + barrier C make cross-step red reuse safe: a wave can write
    // red parity p for step t+2 only after barrier C(t+1), which wave0 joins
    // strictly after its red(t) reads (parity p) complete.
  }
}

// ---------------------------------------------------------------------------
extern "C" void kernel_launch(void* const* d_in, const int* in_sizes, int n_in,
                              void* d_out, int out_size, void* d_ws, size_t ws_size,
                              hipStream_t stream)
{
  (void)in_sizes; (void)n_in; (void)out_size; (void)ws_size;
  const float* x    = (const float*)d_in[0];
  const float* h0   = (const float*)d_in[1];
  const float* Win  = (const float*)d_in[2];
  const float* Wx   = (const float*)d_in[3];
  const float* Wh   = (const float*)d_in[4];
  const float* bias = (const float*)d_in[5];
  const float* lal  = (const float*)d_in[6];
  const float* Wout = (const float*)d_in[7];

  char* ws = (char*)d_ws;
  float*    U     = (float*)(ws);                    // 67,108,864 B (fp32 u)
  _Float16* OUTS  = (_Float16*)(ws);                 // aliases U (U dead after GEMM2)
  _Float16* WoutF = (_Float16*)(ws + 67108864);      //  8,388,608 B
  char*     hpub  = ws + 75497472;                   //    131,072 B chunk-transposed
  int*      flags = (int*)(ws + 75628544);           //        512 B
  float*    wxbuf = (float*)d_out;                   // wx staged in d_out

  const dim3 gg(16, 64);  // N/128, M/128

  k_convert<<<512, 256, 0, stream>>>(Wout, h0, WoutF, hpub, flags);
  // u = silu(x . W_in^T)  (split-f16, fp32 out)
  k_gemm_split<0><<<gg, 256, 0, stream>>>(x, Win, U, nullptr, 8192, 2048, 2048);
  // wx[t][b][:] = u . W_x^T + b  (split-f16, fp32 out in d_out)
  k_gemm_split<1><<<gg, 256, 0, stream>>>(U, Wx, wxbuf, bias, 8192, 2048, 2048);
  // sequential scan; writes outs/8 (f16) over the dead U region
  k_recur<<<128, 256, 0, stream>>>(Wh, wxbuf, h0, lal, OUTS, hpub, flags);
  // y = outs . W_out^T  (epilogue *8), overwrites d_out
  k_gemm_out<<<gg, 256, 0, stream>>>(OUTS, WoutF, (float*)d_out, 8192, 2048, 2048);
}

// Round 12
// 5287.956 us; speedup vs baseline: 1.2367x; 1.1683x over previous
//
#include <hip/hip_runtime.h>

#define DEV static __device__ __forceinline__

typedef _Float16 half8  __attribute__((ext_vector_type(8)));
typedef _Float16 half4v __attribute__((ext_vector_type(4)));
typedef float    floatx4 __attribute__((ext_vector_type(4)));
typedef unsigned int u32;
typedef unsigned long long u64;
typedef u32 u32x4 __attribute__((ext_vector_type(4)));

// Split scale: lo = f16((v - f16(v)) * 1024); combine = hi + lo/1024.
#define SPLIT_S 1024.0f
#define SPLIT_R (1.0f / 1024.0f)

// async global->LDS, 16B/lane: LDS dest wave-uniform base + lane*16.
DEV void gl_lds16(const _Float16* g, _Float16* l) {
  __builtin_amdgcn_global_load_lds(
      (const __attribute__((address_space(1))) u32*)g,
      (__attribute__((address_space(3))) u32*)l, 16, 0, 0);
}

// LLC-coherent (bypass L1/L2) 16B load / stores. Freshness via sc0+sc1.
DEV u32x4 llc_load16(u64 addr) {
  u32x4 r;
  asm volatile("global_load_dwordx4 %0, %1, off sc0 sc1"
               : "=v"(r) : "v"(addr));
  return r;
}
DEV void llc_store8(u64 addr, u64 v) {
  asm volatile("global_store_dwordx2 %0, %1, off sc0 sc1"
               :: "v"(addr), "v"(v) : "memory");
}
// No-return atomic add: completes at the coherence point, device-visible.
DEV void mall_add4(u64 addr, int v) {
  asm volatile("global_atomic_add %0, %1, off"
               :: "v"(addr), "v"(v) : "memory");
}

// Overflow-safe fast tanh: tanh(x) = sign(x) * (1 - 2/(1+e^{2|x|})).
DEV float fast_tanh(float x) {
  const float e = __expf(2.0f * fabsf(x));
  return copysignf(1.0f - 2.0f / (1.0f + e), x);
}

// ---------------------------------------------------------------------------
// h_pub CHUNK-TRANSPOSED layout (bytes):
//   [parity(2) stride 65536][part(2) stride 32768][kchunk(256) stride 128][row(8) stride 16]
// 16B unit = h[row][kchunk*8 .. +8) as f16. Consumer gather is coalesced AND
// fragment-exact (no LDS staging, no shuffles).
// Sync: 8 u32 counters packed in ONE 64B line; WG g bumps counter[g>>4] once
// per step after its h(t+1) is globally visible. counter[i] == 16*(t+1) when
// all 16 member WGs of group i finished step t.
// Convert W_out->f16; init h_pub parity0 = split(h0); zero counters.
__global__ __launch_bounds__(256) void k_convert(
    const float* __restrict__ wout, const float* __restrict__ h0,
    _Float16* __restrict__ WoutF, char* __restrict__ hpub,
    int* __restrict__ counters)
{
  if (blockIdx.x == 0 && threadIdx.x < 16) counters[threadIdx.x] = 0;
  const int NW4 = (2048 * 2048) / 4;
  for (int i = blockIdx.x * 256 + threadIdx.x; i < NW4; i += gridDim.x * 256) {
    const float4 v = ((const float4*)wout)[i];
    half4v o;
    o[0] = (_Float16)v.x; o[1] = (_Float16)v.y;
    o[2] = (_Float16)v.z; o[3] = (_Float16)v.w;
    ((half4v*)WoutF)[i] = o;
  }
  // 2048 cells: chunk c = id>>3 (256), row b = id&7.
  for (int id = blockIdx.x * 256 + threadIdx.x; id < 2048; id += gridDim.x * 256) {
    const int c = id >> 3, b = id & 7;
    union { _Float16 h[8]; u32x4 v; } hi, lo;
#pragma unroll
    for (int j = 0; j < 8; ++j) {
      const float v = h0[b * 2048 + c * 8 + j];
      const _Float16 h = (_Float16)v;
      hi.h[j] = h;
      lo.h[j] = (_Float16)((v - (float)h) * SPLIT_S);
    }
    *(u32x4*)(hpub + c * 128 + b * 16)         = hi.v;
    *(u32x4*)(hpub + 32768 + c * 128 + b * 16) = lo.v;
  }
}

// ---------------------------------------------------------------------------
// Split-f16 GEMM: C[m,n] = sum_k A[m,k]*B[n,k], A/B fp32 row-major (MxK, NxK).
// EPI 0: C = silu(v) fp32.  EPI 1: C[(t*8+b)*N+n] = v + bias[n] fp32.
template <int EPI>
__global__ __launch_bounds__(256) void k_gemm_split(
    const float* __restrict__ A, const float* __restrict__ B,
    float* __restrict__ C, const float* __restrict__ bias,
    int M, int N, int K)
{
  __shared__ _Float16 Ah[4096], Al[4096], Bh[4096], Bl[4096];
  const int tid  = threadIdx.x;
  const int lane = tid & 63, wave = tid >> 6;
  const int wm = wave >> 1, wn = wave & 1;
  const int tm = blockIdx.y * 128, tn = blockIdx.x * 128;
  const int lr = lane & 15, lk = lane >> 4;

  floatx4 acch[4][4] = {};
  floatx4 accl[4][4] = {};

  for (int k0 = 0; k0 < K; k0 += 32) {
    float4 av[4], bv[4];
#pragma unroll
    for (int q = 0; q < 4; ++q) {
      const int c = tid + q * 256;           // chunk 0..1023 (float4 units)
      const int rr = c >> 3, cc = (c & 7) * 4;
      av[q] = *(const float4*)(A + (size_t)(tm + rr) * K + k0 + cc);
      bv[q] = *(const float4*)(B + (size_t)(tn + rr) * K + k0 + cc);
    }
    __syncthreads();   // previous iteration's frag reads complete
#pragma unroll
    for (int q = 0; q < 4; ++q) {
      const int c = tid + q * 256;
      const int rr = c >> 3, cc = (c & 7) * 4;
      half4v ah, al, bh, bl;
#pragma unroll
      for (int j = 0; j < 4; ++j) {
        const float xa = av[q][j], xb = bv[q][j];
        const _Float16 ha = (_Float16)xa, hb = (_Float16)xb;
        ah[j] = ha; al[j] = (_Float16)((xa - (float)ha) * SPLIT_S);
        bh[j] = hb; bl[j] = (_Float16)((xb - (float)hb) * SPLIT_S);
      }
      *(half4v*)(Ah + rr * 32 + cc) = ah;
      *(half4v*)(Al + rr * 32 + cc) = al;
      *(half4v*)(Bh + rr * 32 + cc) = bh;
      *(half4v*)(Bl + rr * 32 + cc) = bl;
    }
    __syncthreads();

    half8 fah[4], fal[4], fbh[4], fbl[4];
#pragma unroll
    for (int mi = 0; mi < 4; ++mi) {
      const int off = (wm * 64 + mi * 16 + lr) * 32 + lk * 8;
      fah[mi] = *(const half8*)(Ah + off);
      fal[mi] = *(const half8*)(Al + off);
    }
#pragma unroll
    for (int ni = 0; ni < 4; ++ni) {
      const int off = (wn * 64 + ni * 16 + lr) * 32 + lk * 8;
      fbh[ni] = *(const half8*)(Bh + off);
      fbl[ni] = *(const half8*)(Bl + off);
    }
#pragma unroll
    for (int mi = 0; mi < 4; ++mi)
#pragma unroll
      for (int ni = 0; ni < 4; ++ni) {
        acch[mi][ni] = __builtin_amdgcn_mfma_f32_16x16x32_f16(fah[mi], fbh[ni], acch[mi][ni], 0, 0, 0);
        accl[mi][ni] = __builtin_amdgcn_mfma_f32_16x16x32_f16(
            fah[mi], fbl[ni],
            __builtin_amdgcn_mfma_f32_16x16x32_f16(fal[mi], fbh[ni], accl[mi][ni], 0, 0, 0),
            0, 0, 0);
      }
  }

#pragma unroll
  for (int mi = 0; mi < 4; ++mi)
#pragma unroll
    for (int ni = 0; ni < 4; ++ni) {
      const int gcol = tn + wn * 64 + ni * 16 + lr;
#pragma unroll
      for (int r = 0; r < 4; ++r) {
        const int grow = tm + wm * 64 + mi * 16 + lk * 4 + r;
        const float v = acch[mi][ni][r] + accl[mi][ni][r] * SPLIT_R;
        if (EPI == 0) {
          C[(size_t)grow * N + gcol] = v / (1.0f + __expf(-v));
        } else {
          const int tt = grow & 1023, bb = grow >> 10;
          C[(size_t)(tt * 8 + bb) * N + gcol] = v + bias[gcol];
        }
      }
    }
}

// ---------------------------------------------------------------------------
// Plain-f16 GEMM for y = (outs/8) . Wout^T, epilogue *8.
__global__ __launch_bounds__(256) void k_gemm_out(
    const _Float16* __restrict__ A, const _Float16* __restrict__ B,
    float* __restrict__ C, int M, int N, int K)
{
  __shared__ _Float16 As[4096];
  __shared__ _Float16 Bs[4096];
  const int tid  = threadIdx.x;
  const int lane = tid & 63, wave = tid >> 6;
  const int wm = wave >> 1, wn = wave & 1;
  const int tm = blockIdx.y * 128, tn = blockIdx.x * 128;
  const int lr = lane & 15, lk = lane >> 4;
  const int r0 = tid >> 2;
  const int c0 = (tid & 3) * 8;

  floatx4 acc[4][4] = {};

  for (int k0 = 0; k0 < K; k0 += 32) {
#pragma unroll
    for (int c = 0; c < 2; ++c) {
      const int row = c * 64 + r0;
      gl_lds16(A + (size_t)(tm + row) * K + k0 + c0, As + c * 2048 + wave * 512);
      gl_lds16(B + (size_t)(tn + row) * K + k0 + c0, Bs + c * 2048 + wave * 512);
    }
    __syncthreads();

    half8 af[4], bf[4];
#pragma unroll
    for (int mi = 0; mi < 4; ++mi)
      af[mi] = *(const half8*)(As + (wm * 64 + mi * 16 + lr) * 32 + lk * 8);
#pragma unroll
    for (int ni = 0; ni < 4; ++ni)
      bf[ni] = *(const half8*)(Bs + (wn * 64 + ni * 16 + lr) * 32 + lk * 8);
#pragma unroll
    for (int mi = 0; mi < 4; ++mi)
#pragma unroll
      for (int ni = 0; ni < 4; ++ni)
        acc[mi][ni] = __builtin_amdgcn_mfma_f32_16x16x32_f16(af[mi], bf[ni], acc[mi][ni], 0, 0, 0);
    __syncthreads();
  }

#pragma unroll
  for (int mi = 0; mi < 4; ++mi)
#pragma unroll
    for (int ni = 0; ni < 4; ++ni) {
      const int gcol = tn + wn * 64 + ni * 16 + lr;
#pragma unroll
      for (int r = 0; r < 4; ++r) {
        const int grow = tm + wm * 64 + mi * 16 + lk * 4 + r;
        C[(size_t)grow * N + gcol] = acc[mi][ni][r] * 8.0f;
      }
    }
}

// ---------------------------------------------------------------------------
// Persistent recurrence, split-f16 — r7 structure (proven 3.60 ms) with two
// surgical changes:
//   (a) detection via 8 packed counters (ONE 64B line): consumer sample =
//       one coalesced 32B read/WG (8x less poll traffic than 8-line flags);
//   (b) producer release reorder: outs-VALU computed between h-store issue
//       and vmcnt(0), hiding most of the store-ack latency.
// 128 WGs x 256 thr (1 WG/CU). Per step:
//   poll(wave0, counters) -> barrier A -> register-direct gather (vmcnt(16)
//   hi/lo overlap) -> 48 MFMA -> red -> barrier C -> wave0 tail:
//   reduce, tanh, h stores, ov compute, vmcnt(0), counter add, outs.
__global__ __launch_bounds__(256, 1) void k_recur(
    const float* __restrict__ Wh, const float* __restrict__ wxp,
    const float* __restrict__ h0p, const float* __restrict__ lalpha,
    _Float16* __restrict__ outs, char* __restrict__ h_pub, int* counters)
{
  __shared__ float red[256 * 4];   // 4KB (cross-wave reduce only)
  const int tid = threadIdx.x;
  const int lane = tid & 63, wave = tid >> 6;
  const int g = blockIdx.x;
  const int e0 = g * 16;
  const int lr = lane & 15, lk = lane >> 4;
  const int lrc = lr & 7;   // lanes lr>=8 duplicate row lr-8 (dead B cols)
  const float alpha = __expf(lalpha[0]);

  // Preload + split W_h fragments (fp32 global -> hi/lo f16 regs), once.
  half8 afh[16], afl[16];
#pragma unroll
  for (int ks = 0; ks < 16; ++ks) {
    const float* wp = Wh + (size_t)(e0 + lr) * 2048 + wave * 512 + ks * 32 + lk * 8;
    const float4 f0 = *(const float4*)wp;
    const float4 f1 = *(const float4*)(wp + 4);
    half8 h, l;
#pragma unroll
    for (int j = 0; j < 4; ++j) {
      const float a0 = ((const float*)&f0)[j], a1 = ((const float*)&f1)[j];
      const _Float16 h0_ = (_Float16)a0;
      const _Float16 h1_ = (_Float16)a1;
      h[j]     = h0_; l[j]     = (_Float16)((a0 - (float)h0_) * SPLIT_S);
      h[j + 4] = h1_; l[j + 4] = (_Float16)((a1 - (float)h1_) * SPLIT_S);
    }
    afh[ks] = h; afl[ks] = l;
  }

  const bool owner = (tid < 64) && (lr < 8);  // owns (batch lr, cols e0+lk*4..+4)
  float hr0 = 0.f, hr1 = 0.f, hr2 = 0.f, hr3 = 0.f;
  if (owner) {
    const float4 hv = *(const float4*)(h0p + (size_t)lr * 2048 + e0 + lk * 4);
    hr0 = hv.x; hr1 = hv.y; hr2 = hv.z; hr3 = hv.w;
  }

  const u64 hbase = (u64)h_pub;
  const u64 cnt_base = (u64)counters;
  // Per-lane gather base: chunk (wave*64 + ks*4 + lk), row lrc.
  const u64 gb_off = (u64)((wave * 64 + lk) * 128 + lrc * 16);

  for (int t = 0; t < 1024; ++t) {
    // Prefetch wx_t (plain cached; consumed in tail, hidden under poll+gather).
    float4 wv = {0.f, 0.f, 0.f, 0.f};
    if (owner) wv = *(const float4*)(wxp + (size_t)(t * 8 + lr) * 2048 + e0 + lk * 4);

    // Poll: wave 0 only; ONE coalesced 32B sample of the packed counter line.
    if (t > 0 && wave == 0) {
      const int thr = 16 * t;
      const int* cp = counters + (lane & 7);
      for (;;) {
        const int cv = __hip_atomic_load(cp, __ATOMIC_RELAXED, __HIP_MEMORY_SCOPE_AGENT);
        if (__all(cv >= thr)) break;
        __builtin_amdgcn_s_sleep(1);
      }
    }
    __syncthreads();   // A

    // ---- register-direct gather: hi then lo, all 32 loads in flight ----
    const u64 pb = hbase + (u64)(t & 1) * 65536 + gb_off;
    u32x4 sh[16], sl[16];
#pragma unroll
    for (int ks = 0; ks < 16; ++ks) sh[ks] = llc_load16(pb + (u64)ks * 512);
#pragma unroll
    for (int ks = 0; ks < 16; ++ks) sl[ks] = llc_load16(pb + 32768 + (u64)ks * 512);
    asm volatile("s_waitcnt vmcnt(16)" ::: "memory");   // hi complete
    __builtin_amdgcn_sched_barrier(0);

    // ---- hi MFMAs: ph += Ah.Bh ; pl += Al.Bh (lo loads still in flight) ----
    floatx4 ph[4] = {};
    floatx4 pl[4] = {};
#pragma unroll
    for (int ks = 0; ks < 16; ++ks) {
      const half8 bh = __builtin_bit_cast(half8, sh[ks]);
      ph[ks & 3] = __builtin_amdgcn_mfma_f32_16x16x32_f16(afh[ks], bh, ph[ks & 3], 0, 0, 0);
      pl[ks & 3] = __builtin_amdgcn_mfma_f32_16x16x32_f16(afl[ks], bh, pl[ks & 3], 0, 0, 0);
    }
    asm volatile("s_waitcnt vmcnt(0)" ::: "memory");    // lo complete
    __builtin_amdgcn_sched_barrier(0);

    // ---- lo MFMAs: pl += Ah.Bl ----
#pragma unroll
    for (int ks = 0; ks < 16; ++ks) {
      const half8 bl = __builtin_bit_cast(half8, sl[ks]);
      pl[ks & 3] = __builtin_amdgcn_mfma_f32_16x16x32_f16(afh[ks], bl, pl[ks & 3], 0, 0, 0);
    }
    const floatx4 pt = (ph[0] + ph[1] + ph[2] + ph[3]) +
                       (pl[0] + pl[1] + pl[2] + pl[3]) * SPLIT_R;
    *(floatx4*)&red[(wave * 64 + lane) * 4] = pt;
    __syncthreads();   // C

    if (tid < 64) {
      const floatx4* R = (const floatx4*)red;
      const floatx4 s = R[lane] + R[64 + lane] + R[128 + lane] + R[192 + lane];
      union { _Float16 h[4]; u64 u; } hv, lv, ov;
      if (owner) {
        hr0 += alpha * fast_tanh(s[0] + wv.x);
        hr1 += alpha * fast_tanh(s[1] + wv.y);
        hr2 += alpha * fast_tanh(s[2] + wv.z);
        hr3 += alpha * fast_tanh(s[3] + wv.w);
        hv.h[0] = (_Float16)hr0; hv.h[1] = (_Float16)hr1;
        hv.h[2] = (_Float16)hr2; hv.h[3] = (_Float16)hr3;
        lv.h[0] = (_Float16)((hr0 - (float)hv.h[0]) * SPLIT_S);
        lv.h[1] = (_Float16)((hr1 - (float)hv.h[1]) * SPLIT_S);
        lv.h[2] = (_Float16)((hr2 - (float)hv.h[2]) * SPLIT_S);
        lv.h[3] = (_Float16)((hr3 - (float)hv.h[3]) * SPLIT_S);
        // Transposed-chunk publish: chunk 2g+(lk>>1), row lr, byte-half (lk&1).
        const u64 dst = hbase + (u64)((t + 1) & 1) * 65536 +
                        (u64)((2 * g + (lk >> 1)) * 128 + lr * 16 + (lk & 1) * 8);
        llc_store8(dst,         hv.u);   // hi   (fly during ov computation)
        llc_store8(dst + 32768, lv.u);   // lo
        // Compute outs payload NOW -> hides most of the h-store ack latency.
        ov.h[0] = (_Float16)((hr0 * hr0 / (1.f + __expf(-hr0))) * 0.125f);
        ov.h[1] = (_Float16)((hr1 * hr1 / (1.f + __expf(-hr1))) * 0.125f);
        ov.h[2] = (_Float16)((hr2 * hr2 / (1.f + __expf(-hr2))) * 0.125f);
        ov.h[3] = (_Float16)((hr3 * hr3 / (1.f + __expf(-hr3))) * 0.125f);
      }
      // Ack h stores (mostly drained already), then bump the group counter.
      asm volatile("s_waitcnt vmcnt(0)" ::: "memory");
      if (lane == 0) mall_add4(cnt_base + (u64)(g >> 4) * 4, 1);
      if (owner)
        *(u64*)(outs + (size_t)(lr * 1024 + t) * 2048 + e0 + lk * 4) = ov.u;
    }
    // red overwrite for t+1 is safe: waves block at barrier A until wave0
    // (which finished its red reads) arrives there after the tail.
  }
}

// ---------------------------------------------------------------------------
extern "C" void kernel_launch(void* const* d_in, const int* in_sizes, int n_in,
                              void* d_out, int out_size, void* d_ws, size_t ws_size,
                              hipStream_t stream)
{
  (void)in_sizes; (void)n_in; (void)out_size; (void)ws_size;
  const float* x    = (const float*)d_in[0];
  const float* h0   = (const float*)d_in[1];
  const float* Win  = (const float*)d_in[2];
  const float* Wx   = (const float*)d_in[3];
  const float* Wh   = (const float*)d_in[4];
  const float* bias = (const float*)d_in[5];
  const float* lal  = (const float*)d_in[6];
  const float* Wout = (const float*)d_in[7];

  char* ws = (char*)d_ws;
  float*    U     = (float*)(ws);                    // 67,108,864 B (fp32 u)
  _Float16* OUTS  = (_Float16*)(ws);                 // aliases U (U dead after GEMM2)
  _Float16* WoutF = (_Float16*)(ws + 67108864);      //  8,388,608 B
  char*     hpub  = ws + 75497472;                   //    131,072 B chunk-transposed
  int*      cnts  = (int*)(ws + 75628544);           //  64 B (8 counters, 1 line)
  float*    wxbuf = (float*)d_out;                   // wx staged in d_out

  const dim3 gg(16, 64);  // N/128, M/128

  k_convert<<<512, 256, 0, stream>>>(Wout, h0, WoutF, hpub, cnts);
  // u = silu(x . W_in^T)  (split-f16, fp32 out)
  k_gemm_split<0><<<gg, 256, 0, stream>>>(x, Win, U, nullptr, 8192, 2048, 2048);
  // wx[t][b][:] = u . W_x^T + b  (split-f16, fp32 out in d_out)
  k_gemm_split<1><<<gg, 256, 0, stream>>>(U, Wx, wxbuf, bias, 8192, 2048, 2048);
  // sequential scan; writes outs/8 (f16) over the dead U region
  k_recur<<<128, 256, 0, stream>>>(Wh, wxbuf, h0, lal, OUTS, hpub, cnts);
  // y = outs . W_out^T  (epilogue *8), overwrites d_out
  k_gemm_out<<<gg, 256, 0, stream>>>(OUTS, WoutF, (float*)d_out, 8192, 2048, 2048);
}

// Round 13
// 4463.715 us; speedup vs baseline: 1.4650x; 1.1847x over previous
//
#include <hip/hip_runtime.h>

#define DEV static __device__ __forceinline__

typedef _Float16 half8  __attribute__((ext_vector_type(8)));
typedef _Float16 half4v __attribute__((ext_vector_type(4)));
typedef float    floatx4 __attribute__((ext_vector_type(4)));
typedef unsigned int u32;
typedef unsigned long long u64;
typedef u32 u32x4 __attribute__((ext_vector_type(4)));

// Split scale: lo = f16((v - f16(v)) * 1024); combine = hi + lo/1024.
#define SPLIT_S 1024.0f
#define SPLIT_R (1.0f / 1024.0f)

// async global->LDS, 16B/lane: LDS dest wave-uniform base + lane*16.
DEV void gl_lds16(const _Float16* g, _Float16* l) {
  __builtin_amdgcn_global_load_lds(
      (const __attribute__((address_space(1))) u32*)g,
      (__attribute__((address_space(3))) u32*)l, 16, 0, 0);
}

// LLC-coherent (bypass L1/L2) 16B load / stores. Freshness via sc0+sc1.
DEV u32x4 llc_load16(u64 addr) {
  u32x4 r;
  asm volatile("global_load_dwordx4 %0, %1, off sc0 sc1"
               : "=v"(r) : "v"(addr));
  return r;
}
DEV void llc_store8(u64 addr, u64 v) {
  asm volatile("global_store_dwordx2 %0, %1, off sc0 sc1"
               :: "v"(addr), "v"(v) : "memory");
}
DEV void llc_store4(u64 addr, int v) {
  asm volatile("global_store_dword %0, %1, off sc0 sc1"
               :: "v"(addr), "v"(v) : "memory");
}

// Overflow-safe fast tanh: tanh(x) = sign(x) * (1 - 2/(1+e^{2|x|})).
DEV float fast_tanh(float x) {
  const float e = __expf(2.0f * fabsf(x));
  return copysignf(1.0f - 2.0f / (1.0f + e), x);
}

// ---------------------------------------------------------------------------
// ws layout (bytes):
//   0         : Uhi [8192][2048] f16 (33,554,432)   -> OUTS aliases this later
//   33554432  : Ulo [8192][2048] f16 (33,554,432)   -> WoutF aliases this later
//   67108864  : Wxhi [2048][2048] f16 (8,388,608)
//   75497472  : Wxlo [2048][2048] f16 (8,388,608)
//   83886080  : hpub (131,072) chunk-transposed
//   84017152  : flags (512)
// wx (fp32, [t][b][d]) staged in d_out.
// ---------------------------------------------------------------------------
// Convert Wx -> hi/lo f16; init h_pub parity0 = split(h0); zero flags.
// h_pub CHUNK-TRANSPOSED layout (bytes):
//   [parity(2) stride 65536][part(2) stride 32768][kchunk(256) stride 128][row(8) stride 16]
__global__ __launch_bounds__(256) void k_convert(
    const float* __restrict__ wx, const float* __restrict__ h0,
    _Float16* __restrict__ Wxhi, _Float16* __restrict__ Wxlo,
    char* __restrict__ hpub, int* __restrict__ flags)
{
  if (blockIdx.x == 0 && threadIdx.x < 128) flags[threadIdx.x] = 0;
  const int NW4 = (2048 * 2048) / 4;
  for (int i = blockIdx.x * 256 + threadIdx.x; i < NW4; i += gridDim.x * 256) {
    const float4 v = ((const float4*)wx)[i];
    half4v h, l;
#pragma unroll
    for (int j = 0; j < 4; ++j) {
      const float a = ((const float*)&v)[j];
      const _Float16 hh = (_Float16)a;
      h[j] = hh;
      l[j] = (_Float16)((a - (float)hh) * SPLIT_S);
    }
    ((half4v*)Wxhi)[i] = h;
    ((half4v*)Wxlo)[i] = l;
  }
  // 2048 cells: chunk c = id>>3 (256), row b = id&7.
  for (int id = blockIdx.x * 256 + threadIdx.x; id < 2048; id += gridDim.x * 256) {
    const int c = id >> 3, b = id & 7;
    union { _Float16 h[8]; u32x4 v; } hi, lo;
#pragma unroll
    for (int j = 0; j < 8; ++j) {
      const float v = h0[b * 2048 + c * 8 + j];
      const _Float16 h = (_Float16)v;
      hi.h[j] = h;
      lo.h[j] = (_Float16)((v - (float)h) * SPLIT_S);
    }
    *(u32x4*)(hpub + c * 128 + b * 16)         = hi.v;
    *(u32x4*)(hpub + 32768 + c * 128 + b * 16) = lo.v;
  }
}

// Convert Wout -> f16 (runs after GEMM2, into the dead Ulo region).
__global__ __launch_bounds__(256) void k_convert2(
    const float* __restrict__ wout, _Float16* __restrict__ WoutF)
{
  const int NW4 = (2048 * 2048) / 4;
  for (int i = blockIdx.x * 256 + threadIdx.x; i < NW4; i += gridDim.x * 256) {
    const float4 v = ((const float4*)wout)[i];
    half4v o;
    o[0] = (_Float16)v.x; o[1] = (_Float16)v.y;
    o[2] = (_Float16)v.z; o[3] = (_Float16)v.w;
    ((half4v*)WoutF)[i] = o;
  }
}

// ---------------------------------------------------------------------------
// GEMM1: split-f16 from fp32 operands (reg-staged, on-the-fly split).
// C[m,n] = silu(sum_k A[m,k]*B[n,k]) written as PRE-SPLIT hi/lo f16.
__global__ __launch_bounds__(256) void k_gemm1(
    const float* __restrict__ A, const float* __restrict__ B,
    _Float16* __restrict__ Chi, _Float16* __restrict__ Clo,
    int M, int N, int K)
{
  __shared__ _Float16 Ah[4096], Al[4096], Bh[4096], Bl[4096];
  const int tid  = threadIdx.x;
  const int lane = tid & 63, wave = tid >> 6;
  const int wm = wave >> 1, wn = wave & 1;
  const int tm = blockIdx.y * 128, tn = blockIdx.x * 128;
  const int lr = lane & 15, lk = lane >> 4;

  floatx4 acch[4][4] = {};
  floatx4 accl[4][4] = {};

  for (int k0 = 0; k0 < K; k0 += 32) {
    float4 av[4], bv[4];
#pragma unroll
    for (int q = 0; q < 4; ++q) {
      const int c = tid + q * 256;           // chunk 0..1023 (float4 units)
      const int rr = c >> 3, cc = (c & 7) * 4;
      av[q] = *(const float4*)(A + (size_t)(tm + rr) * K + k0 + cc);
      bv[q] = *(const float4*)(B + (size_t)(tn + rr) * K + k0 + cc);
    }
    __syncthreads();   // previous iteration's frag reads complete
#pragma unroll
    for (int q = 0; q < 4; ++q) {
      const int c = tid + q * 256;
      const int rr = c >> 3, cc = (c & 7) * 4;
      half4v ah, al, bh, bl;
#pragma unroll
      for (int j = 0; j < 4; ++j) {
        const float xa = av[q][j], xb = bv[q][j];
        const _Float16 ha = (_Float16)xa, hb = (_Float16)xb;
        ah[j] = ha; al[j] = (_Float16)((xa - (float)ha) * SPLIT_S);
        bh[j] = hb; bl[j] = (_Float16)((xb - (float)hb) * SPLIT_S);
      }
      *(half4v*)(Ah + rr * 32 + cc) = ah;
      *(half4v*)(Al + rr * 32 + cc) = al;
      *(half4v*)(Bh + rr * 32 + cc) = bh;
      *(half4v*)(Bl + rr * 32 + cc) = bl;
    }
    __syncthreads();

    half8 fah[4], fal[4], fbh[4], fbl[4];
#pragma unroll
    for (int mi = 0; mi < 4; ++mi) {
      const int off = (wm * 64 + mi * 16 + lr) * 32 + lk * 8;
      fah[mi] = *(const half8*)(Ah + off);
      fal[mi] = *(const half8*)(Al + off);
    }
#pragma unroll
    for (int ni = 0; ni < 4; ++ni) {
      const int off = (wn * 64 + ni * 16 + lr) * 32 + lk * 8;
      fbh[ni] = *(const half8*)(Bh + off);
      fbl[ni] = *(const half8*)(Bl + off);
    }
#pragma unroll
    for (int mi = 0; mi < 4; ++mi)
#pragma unroll
      for (int ni = 0; ni < 4; ++ni) {
        acch[mi][ni] = __builtin_amdgcn_mfma_f32_16x16x32_f16(fah[mi], fbh[ni], acch[mi][ni], 0, 0, 0);
        accl[mi][ni] = __builtin_amdgcn_mfma_f32_16x16x32_f16(
            fah[mi], fbl[ni],
            __builtin_amdgcn_mfma_f32_16x16x32_f16(fal[mi], fbh[ni], accl[mi][ni], 0, 0, 0),
            0, 0, 0);
      }
  }

#pragma unroll
  for (int mi = 0; mi < 4; ++mi)
#pragma unroll
    for (int ni = 0; ni < 4; ++ni) {
      const int gcol = tn + wn * 64 + ni * 16 + lr;
#pragma unroll
      for (int r = 0; r < 4; ++r) {
        const int grow = tm + wm * 64 + mi * 16 + lk * 4 + r;
        const float v = acch[mi][ni][r] + accl[mi][ni][r] * SPLIT_R;
        const float s = v / (1.0f + __expf(-v));
        const _Float16 sh = (_Float16)s;
        Chi[(size_t)grow * N + gcol] = sh;
        Clo[(size_t)grow * N + gcol] = (_Float16)((s - (float)sh) * SPLIT_S);
      }
    }
}

// ---------------------------------------------------------------------------
// GEMM2: split-f16 with PRE-SPLIT f16 operands -> pure async staging
// (global_load_lds width-16, zero staging VALU). C = A.B^T + bias at wx
// layout [t][b][d] fp32.
__global__ __launch_bounds__(256) void k_gemm2(
    const _Float16* __restrict__ Ahi, const _Float16* __restrict__ Alo,
    const _Float16* __restrict__ Bhi, const _Float16* __restrict__ Blo,
    float* __restrict__ C, const float* __restrict__ bias,
    int M, int N, int K)
{
  __shared__ _Float16 Ah[4096], Al[4096], Bh[4096], Bl[4096];
  const int tid  = threadIdx.x;
  const int lane = tid & 63, wave = tid >> 6;
  const int wm = wave >> 1, wn = wave & 1;
  const int tm = blockIdx.y * 128, tn = blockIdx.x * 128;
  const int lr = lane & 15, lk = lane >> 4;
  const int r0 = tid >> 2;            // staging row within chunk
  const int c0 = (tid & 3) * 8;       // staging col

  floatx4 acch[4][4] = {};
  floatx4 accl[4][4] = {};

  for (int k0 = 0; k0 < K; k0 += 32) {
#pragma unroll
    for (int c = 0; c < 2; ++c) {
      const int row = c * 64 + r0;
      const size_t aoff = (size_t)(tm + row) * K + k0 + c0;
      const size_t boff = (size_t)(tn + row) * K + k0 + c0;
      gl_lds16(Ahi + aoff, Ah + c * 2048 + wave * 512);
      gl_lds16(Alo + aoff, Al + c * 2048 + wave * 512);
      gl_lds16(Bhi + boff, Bh + c * 2048 + wave * 512);
      gl_lds16(Blo + boff, Bl + c * 2048 + wave * 512);
    }
    __syncthreads();   // drains vmcnt -> staged data visible

    half8 fah[4], fal[4], fbh[4], fbl[4];
#pragma unroll
    for (int mi = 0; mi < 4; ++mi) {
      const int off = (wm * 64 + mi * 16 + lr) * 32 + lk * 8;
      fah[mi] = *(const half8*)(Ah + off);
      fal[mi] = *(const half8*)(Al + off);
    }
#pragma unroll
    for (int ni = 0; ni < 4; ++ni) {
      const int off = (wn * 64 + ni * 16 + lr) * 32 + lk * 8;
      fbh[ni] = *(const half8*)(Bh + off);
      fbl[ni] = *(const half8*)(Bl + off);
    }
#pragma unroll
    for (int mi = 0; mi < 4; ++mi)
#pragma unroll
      for (int ni = 0; ni < 4; ++ni) {
        acch[mi][ni] = __builtin_amdgcn_mfma_f32_16x16x32_f16(fah[mi], fbh[ni], acch[mi][ni], 0, 0, 0);
        accl[mi][ni] = __builtin_amdgcn_mfma_f32_16x16x32_f16(
            fah[mi], fbl[ni],
            __builtin_amdgcn_mfma_f32_16x16x32_f16(fal[mi], fbh[ni], accl[mi][ni], 0, 0, 0),
            0, 0, 0);
      }
    __syncthreads();   // protect LDS before next stage
  }

#pragma unroll
  for (int mi = 0; mi < 4; ++mi)
#pragma unroll
    for (int ni = 0; ni < 4; ++ni) {
      const int gcol = tn + wn * 64 + ni * 16 + lr;
#pragma unroll
      for (int r = 0; r < 4; ++r) {
        const int grow = tm + wm * 64 + mi * 16 + lk * 4 + r;
        const float v = acch[mi][ni][r] + accl[mi][ni][r] * SPLIT_R;
        const int tt = grow & 1023, bb = grow >> 10;
        C[(size_t)(tt * 8 + bb) * N + gcol] = v + bias[gcol];
      }
    }
}

// ---------------------------------------------------------------------------
// Plain-f16 GEMM for y = (outs/8) . Wout^T, epilogue *8.
__global__ __launch_bounds__(256) void k_gemm_out(
    const _Float16* __restrict__ A, const _Float16* __restrict__ B,
    float* __restrict__ C, int M, int N, int K)
{
  __shared__ _Float16 As[4096];
  __shared__ _Float16 Bs[4096];
  const int tid  = threadIdx.x;
  const int lane = tid & 63, wave = tid >> 6;
  const int wm = wave >> 1, wn = wave & 1;
  const int tm = blockIdx.y * 128, tn = blockIdx.x * 128;
  const int lr = lane & 15, lk = lane >> 4;
  const int r0 = tid >> 2;
  const int c0 = (tid & 3) * 8;

  floatx4 acc[4][4] = {};

  for (int k0 = 0; k0 < K; k0 += 32) {
#pragma unroll
    for (int c = 0; c < 2; ++c) {
      const int row = c * 64 + r0;
      gl_lds16(A + (size_t)(tm + row) * K + k0 + c0, As + c * 2048 + wave * 512);
      gl_lds16(B + (size_t)(tn + row) * K + k0 + c0, Bs + c * 2048 + wave * 512);
    }
    __syncthreads();

    half8 af[4], bf[4];
#pragma unroll
    for (int mi = 0; mi < 4; ++mi)
      af[mi] = *(const half8*)(As + (wm * 64 + mi * 16 + lr) * 32 + lk * 8);
#pragma unroll
    for (int ni = 0; ni < 4; ++ni)
      bf[ni] = *(const half8*)(Bs + (wn * 64 + ni * 16 + lr) * 32 + lk * 8);
#pragma unroll
    for (int mi = 0; mi < 4; ++mi)
#pragma unroll
      for (int ni = 0; ni < 4; ++ni)
        acc[mi][ni] = __builtin_amdgcn_mfma_f32_16x16x32_f16(af[mi], bf[ni], acc[mi][ni], 0, 0, 0);
    __syncthreads();
  }

#pragma unroll
  for (int mi = 0; mi < 4; ++mi)
#pragma unroll
    for (int ni = 0; ni < 4; ++ni) {
      const int gcol = tn + wn * 64 + ni * 16 + lr;
#pragma unroll
      for (int r = 0; r < 4; ++r) {
        const int grow = tm + wm * 64 + mi * 16 + lk * 4 + r;
        C[(size_t)grow * N + gcol] = acc[mi][ni][r] * 8.0f;
      }
    }
}

// ---------------------------------------------------------------------------
// Persistent recurrence — EXACT r7 structure (empirical best, 3.60 ms):
// flag protocol + register-direct chunk-transposed gather. 128 WGs x 256 thr.
__global__ __launch_bounds__(256, 1) void k_recur(
    const float* __restrict__ Wh, const float* __restrict__ wxp,
    const float* __restrict__ h0p, const float* __restrict__ lalpha,
    _Float16* __restrict__ outs, char* __restrict__ h_pub, int* flags)
{
  __shared__ float red[256 * 4];   // 4KB (cross-wave reduce only)
  const int tid = threadIdx.x;
  const int lane = tid & 63, wave = tid >> 6;
  const int g = blockIdx.x;
  const int e0 = g * 16;
  const int lr = lane & 15, lk = lane >> 4;
  const int lrc = lr & 7;   // lanes lr>=8 duplicate row lr-8 (dead B cols)
  const float alpha = __expf(lalpha[0]);

  // Preload + split W_h fragments (fp32 global -> hi/lo f16 regs), once.
  half8 afh[16], afl[16];
#pragma unroll
  for (int ks = 0; ks < 16; ++ks) {
    const float* wp = Wh + (size_t)(e0 + lr) * 2048 + wave * 512 + ks * 32 + lk * 8;
    const float4 f0 = *(const float4*)wp;
    const float4 f1 = *(const float4*)(wp + 4);
    half8 h, l;
#pragma unroll
    for (int j = 0; j < 4; ++j) {
      const float a0 = ((const float*)&f0)[j], a1 = ((const float*)&f1)[j];
      const _Float16 h0_ = (_Float16)a0;
      const _Float16 h1_ = (_Float16)a1;
      h[j]     = h0_; l[j]     = (_Float16)((a0 - (float)h0_) * SPLIT_S);
      h[j + 4] = h1_; l[j + 4] = (_Float16)((a1 - (float)h1_) * SPLIT_S);
    }
    afh[ks] = h; afl[ks] = l;
  }

  const bool owner = (tid < 64) && (lr < 8);  // owns (batch lr, cols e0+lk*4..+4)
  float hr0 = 0.f, hr1 = 0.f, hr2 = 0.f, hr3 = 0.f;
  if (owner) {
    const float4 hv = *(const float4*)(h0p + (size_t)lr * 2048 + e0 + lk * 4);
    hr0 = hv.x; hr1 = hv.y; hr2 = hv.z; hr3 = hv.w;
  }

  const u64 hbase = (u64)h_pub;
  const u64 flag_base = (u64)flags;
  // Per-lane gather base: chunk (wave*64 + ks*4 + lk), row lrc.
  const u64 gb_off = (u64)((wave * 64 + lk) * 128 + lrc * 16);

  for (int t = 0; t < 1024; ++t) {
    // Prefetch wx_t (plain cached; consumed in tail, hidden under poll+gather).
    float4 wv = {0.f, 0.f, 0.f, 0.f};
    if (owner) wv = *(const float4*)(wxp + (size_t)(t * 8 + lr) * 2048 + e0 + lk * 4);

    // Poll: wave 0 only; lane watches flags[2*lane], flags[2*lane+1].
    if (t > 0 && wave == 0) {
      const u64* fp = (const u64*)flags + lane;
      for (;;) {
        const u64 fv = __hip_atomic_load(fp, __ATOMIC_RELAXED, __HIP_MEMORY_SCOPE_AGENT);
        if (__all(((int)fv >= t) && ((int)(fv >> 32) >= t))) break;
        __builtin_amdgcn_s_sleep(1);
      }
    }
    __syncthreads();   // A

    // ---- register-direct gather: hi then lo, all 32 loads in flight ----
    const u64 pb = hbase + (u64)(t & 1) * 65536 + gb_off;
    u32x4 sh[16], sl[16];
#pragma unroll
    for (int ks = 0; ks < 16; ++ks) sh[ks] = llc_load16(pb + (u64)ks * 512);
#pragma unroll
    for (int ks = 0; ks < 16; ++ks) sl[ks] = llc_load16(pb + 32768 + (u64)ks * 512);
    asm volatile("s_waitcnt vmcnt(16)" ::: "memory");   // hi complete
    __builtin_amdgcn_sched_barrier(0);

    // ---- hi MFMAs: ph += Ah.Bh ; pl += Al.Bh (lo loads still in flight) ----
    floatx4 ph[4] = {};
    floatx4 pl[4] = {};
#pragma unroll
    for (int ks = 0; ks < 16; ++ks) {
      const half8 bh = __builtin_bit_cast(half8, sh[ks]);
      ph[ks & 3] = __builtin_amdgcn_mfma_f32_16x16x32_f16(afh[ks], bh, ph[ks & 3], 0, 0, 0);
      pl[ks & 3] = __builtin_amdgcn_mfma_f32_16x16x32_f16(afl[ks], bh, pl[ks & 3], 0, 0, 0);
    }
    asm volatile("s_waitcnt vmcnt(0)" ::: "memory");    // lo complete
    __builtin_amdgcn_sched_barrier(0);

    // ---- lo MFMAs: pl += Ah.Bl ----
#pragma unroll
    for (int ks = 0; ks < 16; ++ks) {
      const half8 bl = __builtin_bit_cast(half8, sl[ks]);
      pl[ks & 3] = __builtin_amdgcn_mfma_f32_16x16x32_f16(afh[ks], bl, pl[ks & 3], 0, 0, 0);
    }
    const floatx4 pt = (ph[0] + ph[1] + ph[2] + ph[3]) +
                       (pl[0] + pl[1] + pl[2] + pl[3]) * SPLIT_R;
    *(floatx4*)&red[(wave * 64 + lane) * 4] = pt;
    __syncthreads();   // C

    if (tid < 64) {
      const floatx4* R = (const floatx4*)red;
      const floatx4 s = R[lane] + R[64 + lane] + R[128 + lane] + R[192 + lane];
      union { _Float16 h[4]; u64 u; } hv, lv, ov;
      if (owner) {
        hr0 += alpha * fast_tanh(s[0] + wv.x);
        hr1 += alpha * fast_tanh(s[1] + wv.y);
        hr2 += alpha * fast_tanh(s[2] + wv.z);
        hr3 += alpha * fast_tanh(s[3] + wv.w);
        hv.h[0] = (_Float16)hr0; hv.h[1] = (_Float16)hr1;
        hv.h[2] = (_Float16)hr2; hv.h[3] = (_Float16)hr3;
        lv.h[0] = (_Float16)((hr0 - (float)hv.h[0]) * SPLIT_S);
        lv.h[1] = (_Float16)((hr1 - (float)hv.h[1]) * SPLIT_S);
        lv.h[2] = (_Float16)((hr2 - (float)hv.h[2]) * SPLIT_S);
        lv.h[3] = (_Float16)((hr3 - (float)hv.h[3]) * SPLIT_S);
        // Transposed-chunk publish: chunk 2g+(lk>>1), row lr, byte-half (lk&1).
        const u64 dst = hbase + (u64)((t + 1) & 1) * 65536 +
                        (u64)((2 * g + (lk >> 1)) * 128 + lr * 16 + (lk & 1) * 8);
        llc_store8(dst,         hv.u);   // hi
        llc_store8(dst + 32768, lv.u);   // lo
      }
      // Ack h stores at LLC, then publish the flag (single dword).
      asm volatile("s_waitcnt vmcnt(0)" ::: "memory");
      if (lane == 0) llc_store4(flag_base + (u64)g * 4, t + 1);
      if (owner) {
        // outs consumed only by the next dispatch -> off the critical path.
        ov.h[0] = (_Float16)((hr0 * hr0 / (1.f + __expf(-hr0))) * 0.125f);
        ov.h[1] = (_Float16)((hr1 * hr1 / (1.f + __expf(-hr1))) * 0.125f);
        ov.h[2] = (_Float16)((hr2 * hr2 / (1.f + __expf(-hr2))) * 0.125f);
        ov.h[3] = (_Float16)((hr3 * hr3 / (1.f + __expf(-hr3))) * 0.125f);
        *(u64*)(outs + (size_t)(lr * 1024 + t) * 2048 + e0 + lk * 4) = ov.u;
      }
    }
    // red overwrite for t+1 is safe: waves block at barrier A until wave0
    // (which finished its red reads) arrives there after the tail.
  }
}

// ---------------------------------------------------------------------------
extern "C" void kernel_launch(void* const* d_in, const int* in_sizes, int n_in,
                              void* d_out, int out_size, void* d_ws, size_t ws_size,
                              hipStream_t stream)
{
  (void)in_sizes; (void)n_in; (void)out_size; (void)ws_size;
  const float* x    = (const float*)d_in[0];
  const float* h0   = (const float*)d_in[1];
  const float* Win  = (const float*)d_in[2];
  const float* Wx   = (const float*)d_in[3];
  const float* Wh   = (const float*)d_in[4];
  const float* bias = (const float*)d_in[5];
  const float* lal  = (const float*)d_in[6];
  const float* Wout = (const float*)d_in[7];

  char* ws = (char*)d_ws;
  _Float16* Uhi   = (_Float16*)(ws);                 // 33,554,432 B
  _Float16* Ulo   = (_Float16*)(ws + 33554432);      // 33,554,432 B
  _Float16* OUTS  = (_Float16*)(ws);                 // aliases Uhi (dead after GEMM2)
  _Float16* WoutF = (_Float16*)(ws + 33554432);      // aliases Ulo (dead after GEMM2)
  _Float16* Wxhi  = (_Float16*)(ws + 67108864);      //  8,388,608 B
  _Float16* Wxlo  = (_Float16*)(ws + 75497472);      //  8,388,608 B
  char*     hpub  = ws + 83886080;                   //    131,072 B chunk-transposed
  int*      flags = (int*)(ws + 84017152);           //        512 B
  float*    wxbuf = (float*)d_out;                   // wx staged in d_out

  const dim3 gg(16, 64);  // N/128, M/128

  // Pre-split Wx; init hpub/flags.
  k_convert<<<512, 256, 0, stream>>>(Wx, h0, Wxhi, Wxlo, hpub, flags);
  // u = silu(x . W_in^T), written pre-split hi/lo f16.
  k_gemm1<<<gg, 256, 0, stream>>>(x, Win, Uhi, Ulo, 8192, 2048, 2048);
  // wx[t][b][:] = u . W_x^T + b  (pure async staging, fp32 out in d_out)
  k_gemm2<<<gg, 256, 0, stream>>>(Uhi, Ulo, Wxhi, Wxlo, wxbuf, bias, 8192, 2048, 2048);
  // Wout -> f16 into the dead Ulo region.
  k_convert2<<<512, 256, 0, stream>>>(Wout, WoutF);
  // sequential scan; writes outs/8 (f16) over the dead Uhi region
  k_recur<<<128, 256, 0, stream>>>(Wh, wxbuf, h0, lal, OUTS, hpub, flags);
  // y = outs . W_out^T  (epilogue *8), overwrites d_out
  k_gemm_out<<<gg, 256, 0, stream>>>(OUTS, WoutF, (float*)d_out, 8192, 2048, 2048);
}

// Round 14
// 4178.598 us; speedup vs baseline: 1.5650x; 1.0682x over previous
//
#include <hip/hip_runtime.h>

#define DEV static __device__ __forceinline__

typedef _Float16 half8  __attribute__((ext_vector_type(8)));
typedef _Float16 half4v __attribute__((ext_vector_type(4)));
typedef float    floatx4 __attribute__((ext_vector_type(4)));
typedef unsigned int u32;
typedef unsigned long long u64;
typedef u32 u32x4 __attribute__((ext_vector_type(4)));

// Split scale: lo = f16((v - f16(v)) * 1024); combine = hi + lo/1024.
#define SPLIT_S 1024.0f
#define SPLIT_R (1.0f / 1024.0f)

// async global->LDS, 16B/lane: LDS dest wave-uniform base + lane*16.
DEV void gl_lds16(const _Float16* g, _Float16* l) {
  __builtin_amdgcn_global_load_lds(
      (const __attribute__((address_space(1))) u32*)g,
      (__attribute__((address_space(3))) u32*)l, 16, 0, 0);
}

// LLC-coherent (bypass L1/L2) 16B load. Freshness via sc0+sc1.
DEV u32x4 llc_load16(u64 addr) {
  u32x4 r;
  asm volatile("global_load_dwordx4 %0, %1, off sc0 sc1"
               : "=v"(r) : "v"(addr));
  return r;
}
// No-return atomic swaps: execute & complete AT the MALL -> cheap vmcnt ack
// (no HBM write-through wait on the critical path). Device-visible.
DEV void mall_swap8(u64 addr, u64 v) {
  asm volatile("global_atomic_swap_x2 %0, %1, off"
               :: "v"(addr), "v"(v) : "memory");
}
DEV void mall_swap4(u64 addr, int v) {
  asm volatile("global_atomic_swap %0, %1, off"
               :: "v"(addr), "v"(v) : "memory");
}

// Overflow-safe fast tanh: tanh(x) = sign(x) * (1 - 2/(1+e^{2|x|})).
DEV float fast_tanh(float x) {
  const float e = __expf(2.0f * fabsf(x));
  return copysignf(1.0f - 2.0f / (1.0f + e), x);
}

// ---------------------------------------------------------------------------
// ws layout (bytes), peak 84.02 MB (proven):
//   0         : Uhi [8192][2048] f16 (33,554,432)  -> OUTS aliases later
//   33554432  : Ulo (33,554,432)                   -> WoutF aliases later
//   67108864  : Whi region (8,388,608)  Win-hi for GEMM1, then Wx-hi for GEMM2
//   75497472  : Wlo region (8,388,608)  Win-lo for GEMM1, then Wx-lo for GEMM2
//   83886080  : hpub (131,072) chunk-transposed
//   84017152  : flags (512)
// d_out: x-splits (xhi 33.5MB + xlo 33.5MB, exactly 67.1MB) until GEMM1 done,
//        then wx fp32 [t][b][d] (GEMM2 output), then y (final).
// ---------------------------------------------------------------------------
// Split x -> d_out (hi/lo f16) and Win -> ws W-region.
__global__ __launch_bounds__(256) void k_split_xw(
    const float* __restrict__ x, const float* __restrict__ win,
    _Float16* __restrict__ xhi, _Float16* __restrict__ xlo,
    _Float16* __restrict__ whi, _Float16* __restrict__ wlo)
{
  const int NX4 = (8192 * 2048) / 4;
  const int NW4 = (2048 * 2048) / 4;
  for (int i = blockIdx.x * 256 + threadIdx.x; i < NX4 + NW4; i += gridDim.x * 256) {
    const float* src; _Float16* dh; _Float16* dl; int j = i;
    if (j < NX4) { src = x; dh = xhi; dl = xlo; }
    else         { j -= NX4; src = win; dh = whi; dl = wlo; }
    const float4 v = ((const float4*)src)[j];
    half4v h, l;
#pragma unroll
    for (int q = 0; q < 4; ++q) {
      const float a = ((const float*)&v)[q];
      const _Float16 hh = (_Float16)a;
      h[q] = hh;
      l[q] = (_Float16)((a - (float)hh) * SPLIT_S);
    }
    ((half4v*)dh)[j] = h;
    ((half4v*)dl)[j] = l;
  }
}

// Split Wx into the W-region (overwrites dead Win splits); init hpub parity0
// = split(h0); zero flags.
// h_pub CHUNK-TRANSPOSED layout (bytes):
//   [parity(2) stride 65536][part(2) stride 32768][kchunk(256) stride 128][row(8) stride 16]
__global__ __launch_bounds__(256) void k_convertB(
    const float* __restrict__ wx, const float* __restrict__ h0,
    _Float16* __restrict__ Wxhi, _Float16* __restrict__ Wxlo,
    char* __restrict__ hpub, int* __restrict__ flags)
{
  if (blockIdx.x == 0 && threadIdx.x < 128) flags[threadIdx.x] = 0;
  const int NW4 = (2048 * 2048) / 4;
  for (int i = blockIdx.x * 256 + threadIdx.x; i < NW4; i += gridDim.x * 256) {
    const float4 v = ((const float4*)wx)[i];
    half4v h, l;
#pragma unroll
    for (int j = 0; j < 4; ++j) {
      const float a = ((const float*)&v)[j];
      const _Float16 hh = (_Float16)a;
      h[j] = hh;
      l[j] = (_Float16)((a - (float)hh) * SPLIT_S);
    }
    ((half4v*)Wxhi)[i] = h;
    ((half4v*)Wxlo)[i] = l;
  }
  for (int id = blockIdx.x * 256 + threadIdx.x; id < 2048; id += gridDim.x * 256) {
    const int c = id >> 3, b = id & 7;
    union { _Float16 h[8]; u32x4 v; } hi, lo;
#pragma unroll
    for (int j = 0; j < 8; ++j) {
      const float v = h0[b * 2048 + c * 8 + j];
      const _Float16 h = (_Float16)v;
      hi.h[j] = h;
      lo.h[j] = (_Float16)((v - (float)h) * SPLIT_S);
    }
    *(u32x4*)(hpub + c * 128 + b * 16)         = hi.v;
    *(u32x4*)(hpub + 32768 + c * 128 + b * 16) = lo.v;
  }
}

// Convert Wout -> f16 (into dead Ulo region).
__global__ __launch_bounds__(256) void k_convert2(
    const float* __restrict__ wout, _Float16* __restrict__ WoutF)
{
  const int NW4 = (2048 * 2048) / 4;
  for (int i = blockIdx.x * 256 + threadIdx.x; i < NW4; i += gridDim.x * 256) {
    const float4 v = ((const float4*)wout)[i];
    half4v o;
    o[0] = (_Float16)v.x; o[1] = (_Float16)v.y;
    o[2] = (_Float16)v.z; o[3] = (_Float16)v.w;
    ((half4v*)WoutF)[i] = o;
  }
}

// ---------------------------------------------------------------------------
// Split-f16 GEMM with PRE-SPLIT f16 operands -> pure async staging
// (global_load_lds width-16, zero staging VALU). C = A.B^T.
// EPI 0: silu -> pre-split hi/lo f16 (GEMM1 -> U).
// EPI 1: + bias -> fp32 at wx layout [t][b][d] (GEMM2 -> wx).
template <int EPI>
__global__ __launch_bounds__(256) void k_gemm_ps(
    const _Float16* __restrict__ Ahi, const _Float16* __restrict__ Alo,
    const _Float16* __restrict__ Bhi, const _Float16* __restrict__ Blo,
    _Float16* __restrict__ Chi, _Float16* __restrict__ Clo,
    float* __restrict__ Cf, const float* __restrict__ bias,
    int M, int N, int K)
{
  __shared__ _Float16 Ah[4096], Al[4096], Bh[4096], Bl[4096];
  const int tid  = threadIdx.x;
  const int lane = tid & 63, wave = tid >> 6;
  const int wm = wave >> 1, wn = wave & 1;
  const int tm = blockIdx.y * 128, tn = blockIdx.x * 128;
  const int lr = lane & 15, lk = lane >> 4;
  const int r0 = tid >> 2;            // staging row within chunk
  const int c0 = (tid & 3) * 8;       // staging col

  floatx4 acch[4][4] = {};
  floatx4 accl[4][4] = {};

  for (int k0 = 0; k0 < K; k0 += 32) {
#pragma unroll
    for (int c = 0; c < 2; ++c) {
      const int row = c * 64 + r0;
      const size_t aoff = (size_t)(tm + row) * K + k0 + c0;
      const size_t boff = (size_t)(tn + row) * K + k0 + c0;
      gl_lds16(Ahi + aoff, Ah + c * 2048 + wave * 512);
      gl_lds16(Alo + aoff, Al + c * 2048 + wave * 512);
      gl_lds16(Bhi + boff, Bh + c * 2048 + wave * 512);
      gl_lds16(Blo + boff, Bl + c * 2048 + wave * 512);
    }
    __syncthreads();   // drains vmcnt -> staged data visible

    half8 fah[4], fal[4], fbh[4], fbl[4];
#pragma unroll
    for (int mi = 0; mi < 4; ++mi) {
      const int off = (wm * 64 + mi * 16 + lr) * 32 + lk * 8;
      fah[mi] = *(const half8*)(Ah + off);
      fal[mi] = *(const half8*)(Al + off);
    }
#pragma unroll
    for (int ni = 0; ni < 4; ++ni) {
      const int off = (wn * 64 + ni * 16 + lr) * 32 + lk * 8;
      fbh[ni] = *(const half8*)(Bh + off);
      fbl[ni] = *(const half8*)(Bl + off);
    }
#pragma unroll
    for (int mi = 0; mi < 4; ++mi)
#pragma unroll
      for (int ni = 0; ni < 4; ++ni) {
        acch[mi][ni] = __builtin_amdgcn_mfma_f32_16x16x32_f16(fah[mi], fbh[ni], acch[mi][ni], 0, 0, 0);
        accl[mi][ni] = __builtin_amdgcn_mfma_f32_16x16x32_f16(
            fah[mi], fbl[ni],
            __builtin_amdgcn_mfma_f32_16x16x32_f16(fal[mi], fbh[ni], accl[mi][ni], 0, 0, 0),
            0, 0, 0);
      }
    __syncthreads();   // protect LDS before next stage
  }

#pragma unroll
  for (int mi = 0; mi < 4; ++mi)
#pragma unroll
    for (int ni = 0; ni < 4; ++ni) {
      const int gcol = tn + wn * 64 + ni * 16 + lr;
#pragma unroll
      for (int r = 0; r < 4; ++r) {
        const int grow = tm + wm * 64 + mi * 16 + lk * 4 + r;
        const float v = acch[mi][ni][r] + accl[mi][ni][r] * SPLIT_R;
        if (EPI == 0) {
          const float s = v / (1.0f + __expf(-v));
          const _Float16 sh = (_Float16)s;
          Chi[(size_t)grow * N + gcol] = sh;
          Clo[(size_t)grow * N + gcol] = (_Float16)((s - (float)sh) * SPLIT_S);
        } else {
          const int tt = grow & 1023, bb = grow >> 10;
          Cf[(size_t)(tt * 8 + bb) * N + gcol] = v + bias[gcol];
        }
      }
    }
}

// ---------------------------------------------------------------------------
// Plain-f16 GEMM for y = (outs/8) . Wout^T, epilogue *8.
__global__ __launch_bounds__(256) void k_gemm_out(
    const _Float16* __restrict__ A, const _Float16* __restrict__ B,
    float* __restrict__ C, int M, int N, int K)
{
  __shared__ _Float16 As[4096];
  __shared__ _Float16 Bs[4096];
  const int tid  = threadIdx.x;
  const int lane = tid & 63, wave = tid >> 6;
  const int wm = wave >> 1, wn = wave & 1;
  const int tm = blockIdx.y * 128, tn = blockIdx.x * 128;
  const int lr = lane & 15, lk = lane >> 4;
  const int r0 = tid >> 2;
  const int c0 = (tid & 3) * 8;

  floatx4 acc[4][4] = {};

  for (int k0 = 0; k0 < K; k0 += 32) {
#pragma unroll
    for (int c = 0; c < 2; ++c) {
      const int row = c * 64 + r0;
      gl_lds16(A + (size_t)(tm + row) * K + k0 + c0, As + c * 2048 + wave * 512);
      gl_lds16(B + (size_t)(tn + row) * K + k0 + c0, Bs + c * 2048 + wave * 512);
    }
    __syncthreads();

    half8 af[4], bf[4];
#pragma unroll
    for (int mi = 0; mi < 4; ++mi)
      af[mi] = *(const half8*)(As + (wm * 64 + mi * 16 + lr) * 32 + lk * 8);
#pragma unroll
    for (int ni = 0; ni < 4; ++ni)
      bf[ni] = *(const half8*)(Bs + (wn * 64 + ni * 16 + lr) * 32 + lk * 8);
#pragma unroll
    for (int mi = 0; mi < 4; ++mi)
#pragma unroll
      for (int ni = 0; ni < 4; ++ni)
        acc[mi][ni] = __builtin_amdgcn_mfma_f32_16x16x32_f16(af[mi], bf[ni], acc[mi][ni], 0, 0, 0);
    __syncthreads();
  }

#pragma unroll
  for (int mi = 0; mi < 4; ++mi)
#pragma unroll
    for (int ni = 0; ni < 4; ++ni) {
      const int gcol = tn + wn * 64 + ni * 16 + lr;
#pragma unroll
      for (int r = 0; r < 4; ++r) {
        const int grow = tm + wm * 64 + mi * 16 + lk * 4 + r;
        C[(size_t)grow * N + gcol] = acc[mi][ni][r] * 8.0f;
      }
    }
}

// ---------------------------------------------------------------------------
// Persistent recurrence — r7 structure (empirical best) with ONE change:
// h + flag published via no-return ATOMIC SWAPS (complete at MALL, ~500cy ack
// instead of ~900cy HBM write-through). Everything else byte-identical.
__global__ __launch_bounds__(256, 1) void k_recur(
    const float* __restrict__ Wh, const float* __restrict__ wxp,
    const float* __restrict__ h0p, const float* __restrict__ lalpha,
    _Float16* __restrict__ outs, char* __restrict__ h_pub, int* flags)
{
  __shared__ float red[256 * 4];   // 4KB (cross-wave reduce only)
  const int tid = threadIdx.x;
  const int lane = tid & 63, wave = tid >> 6;
  const int g = blockIdx.x;
  const int e0 = g * 16;
  const int lr = lane & 15, lk = lane >> 4;
  const int lrc = lr & 7;   // lanes lr>=8 duplicate row lr-8 (dead B cols)
  const float alpha = __expf(lalpha[0]);

  // Preload + split W_h fragments (fp32 global -> hi/lo f16 regs), once.
  half8 afh[16], afl[16];
#pragma unroll
  for (int ks = 0; ks < 16; ++ks) {
    const float* wp = Wh + (size_t)(e0 + lr) * 2048 + wave * 512 + ks * 32 + lk * 8;
    const float4 f0 = *(const float4*)wp;
    const float4 f1 = *(const float4*)(wp + 4);
    half8 h, l;
#pragma unroll
    for (int j = 0; j < 4; ++j) {
      const float a0 = ((const float*)&f0)[j], a1 = ((const float*)&f1)[j];
      const _Float16 h0_ = (_Float16)a0;
      const _Float16 h1_ = (_Float16)a1;
      h[j]     = h0_; l[j]     = (_Float16)((a0 - (float)h0_) * SPLIT_S);
      h[j + 4] = h1_; l[j + 4] = (_Float16)((a1 - (float)h1_) * SPLIT_S);
    }
    afh[ks] = h; afl[ks] = l;
  }

  const bool owner = (tid < 64) && (lr < 8);  // owns (batch lr, cols e0+lk*4..+4)
  float hr0 = 0.f, hr1 = 0.f, hr2 = 0.f, hr3 = 0.f;
  if (owner) {
    const float4 hv = *(const float4*)(h0p + (size_t)lr * 2048 + e0 + lk * 4);
    hr0 = hv.x; hr1 = hv.y; hr2 = hv.z; hr3 = hv.w;
  }

  const u64 hbase = (u64)h_pub;
  const u64 flag_base = (u64)flags;
  // Per-lane gather base: chunk (wave*64 + ks*4 + lk), row lrc.
  const u64 gb_off = (u64)((wave * 64 + lk) * 128 + lrc * 16);

  for (int t = 0; t < 1024; ++t) {
    // Prefetch wx_t (plain cached; consumed in tail, hidden under poll+gather).
    float4 wv = {0.f, 0.f, 0.f, 0.f};
    if (owner) wv = *(const float4*)(wxp + (size_t)(t * 8 + lr) * 2048 + e0 + lk * 4);

    // Poll: wave 0 only; lane watches flags[2*lane], flags[2*lane+1].
    if (t > 0 && wave == 0) {
      const u64* fp = (const u64*)flags + lane;
      for (;;) {
        const u64 fv = __hip_atomic_load(fp, __ATOMIC_RELAXED, __HIP_MEMORY_SCOPE_AGENT);
        if (__all(((int)fv >= t) && ((int)(fv >> 32) >= t))) break;
        __builtin_amdgcn_s_sleep(1);
      }
    }
    __syncthreads();   // A

    // ---- register-direct gather: hi then lo, all 32 loads in flight ----
    const u64 pb = hbase + (u64)(t & 1) * 65536 + gb_off;
    u32x4 sh[16], sl[16];
#pragma unroll
    for (int ks = 0; ks < 16; ++ks) sh[ks] = llc_load16(pb + (u64)ks * 512);
#pragma unroll
    for (int ks = 0; ks < 16; ++ks) sl[ks] = llc_load16(pb + 32768 + (u64)ks * 512);
    asm volatile("s_waitcnt vmcnt(16)" ::: "memory");   // hi complete
    __builtin_amdgcn_sched_barrier(0);

    // ---- hi MFMAs: ph += Ah.Bh ; pl += Al.Bh (lo loads still in flight) ----
    floatx4 ph[4] = {};
    floatx4 pl[4] = {};
#pragma unroll
    for (int ks = 0; ks < 16; ++ks) {
      const half8 bh = __builtin_bit_cast(half8, sh[ks]);
      ph[ks & 3] = __builtin_amdgcn_mfma_f32_16x16x32_f16(afh[ks], bh, ph[ks & 3], 0, 0, 0);
      pl[ks & 3] = __builtin_amdgcn_mfma_f32_16x16x32_f16(afl[ks], bh, pl[ks & 3], 0, 0, 0);
    }
    asm volatile("s_waitcnt vmcnt(0)" ::: "memory");    // lo complete
    __builtin_amdgcn_sched_barrier(0);

    // ---- lo MFMAs: pl += Ah.Bl ----
#pragma unroll
    for (int ks = 0; ks < 16; ++ks) {
      const half8 bl = __builtin_bit_cast(half8, sl[ks]);
      pl[ks & 3] = __builtin_amdgcn_mfma_f32_16x16x32_f16(afh[ks], bl, pl[ks & 3], 0, 0, 0);
    }
    const floatx4 pt = (ph[0] + ph[1] + ph[2] + ph[3]) +
                       (pl[0] + pl[1] + pl[2] + pl[3]) * SPLIT_R;
    *(floatx4*)&red[(wave * 64 + lane) * 4] = pt;
    __syncthreads();   // C

    if (tid < 64) {
      const floatx4* R = (const floatx4*)red;
      const floatx4 s = R[lane] + R[64 + lane] + R[128 + lane] + R[192 + lane];
      union { _Float16 h[4]; u64 u; } hv, lv, ov;
      if (owner) {
        hr0 += alpha * fast_tanh(s[0] + wv.x);
        hr1 += alpha * fast_tanh(s[1] + wv.y);
        hr2 += alpha * fast_tanh(s[2] + wv.z);
        hr3 += alpha * fast_tanh(s[3] + wv.w);
        hv.h[0] = (_Float16)hr0; hv.h[1] = (_Float16)hr1;
        hv.h[2] = (_Float16)hr2; hv.h[3] = (_Float16)hr3;
        lv.h[0] = (_Float16)((hr0 - (float)hv.h[0]) * SPLIT_S);
        lv.h[1] = (_Float16)((hr1 - (float)hv.h[1]) * SPLIT_S);
        lv.h[2] = (_Float16)((hr2 - (float)hv.h[2]) * SPLIT_S);
        lv.h[3] = (_Float16)((hr3 - (float)hv.h[3]) * SPLIT_S);
        // MALL-atomic publish: chunk 2g+(lk>>1), row lr, byte-half (lk&1).
        const u64 dst = hbase + (u64)((t + 1) & 1) * 65536 +
                        (u64)((2 * g + (lk >> 1)) * 128 + lr * 16 + (lk & 1) * 8);
        mall_swap8(dst,         hv.u);   // hi
        mall_swap8(dst + 32768, lv.u);   // lo
      }
      // Ack at MALL (atomics complete at the coherence point), then flag.
      asm volatile("s_waitcnt vmcnt(0)" ::: "memory");
      if (lane == 0) mall_swap4(flag_base + (u64)g * 4, t + 1);
      if (owner) {
        // outs consumed only by the next dispatch -> off the critical path.
        ov.h[0] = (_Float16)((hr0 * hr0 / (1.f + __expf(-hr0))) * 0.125f);
        ov.h[1] = (_Float16)((hr1 * hr1 / (1.f + __expf(-hr1))) * 0.125f);
        ov.h[2] = (_Float16)((hr2 * hr2 / (1.f + __expf(-hr2))) * 0.125f);
        ov.h[3] = (_Float16)((hr3 * hr3 / (1.f + __expf(-hr3))) * 0.125f);
        *(u64*)(outs + (size_t)(lr * 1024 + t) * 2048 + e0 + lk * 4) = ov.u;
      }
    }
    // red overwrite for t+1 is safe: waves block at barrier A until wave0
    // (which finished its red reads) arrives there after the tail.
  }
}

// ---------------------------------------------------------------------------
extern "C" void kernel_launch(void* const* d_in, const int* in_sizes, int n_in,
                              void* d_out, int out_size, void* d_ws, size_t ws_size,
                              hipStream_t stream)
{
  (void)in_sizes; (void)n_in; (void)out_size; (void)ws_size;
  const float* x    = (const float*)d_in[0];
  const float* h0   = (const float*)d_in[1];
  const float* Win  = (const float*)d_in[2];
  const float* Wx   = (const float*)d_in[3];
  const float* Wh   = (const float*)d_in[4];
  const float* bias = (const float*)d_in[5];
  const float* lal  = (const float*)d_in[6];
  const float* Wout = (const float*)d_in[7];

  char* ws = (char*)d_ws;
  _Float16* Uhi   = (_Float16*)(ws);                 // 33,554,432 B
  _Float16* Ulo   = (_Float16*)(ws + 33554432);      // 33,554,432 B
  _Float16* OUTS  = (_Float16*)(ws);                 // aliases Uhi (dead after GEMM2)
  _Float16* WoutF = (_Float16*)(ws + 33554432);      // aliases Ulo (dead after GEMM2)
  _Float16* Whi   = (_Float16*)(ws + 67108864);      //  8,388,608 B (Win then Wx)
  _Float16* Wlo   = (_Float16*)(ws + 75497472);      //  8,388,608 B (Win then Wx)
  char*     hpub  = ws + 83886080;                   //    131,072 B chunk-transposed
  int*      flags = (int*)(ws + 84017152);           //        512 B
  // d_out scratch: x-splits (67.1 MB exactly), later wx fp32, finally y.
  _Float16* xhi   = (_Float16*)d_out;                // 33,554,432 B
  _Float16* xlo   = (_Float16*)((char*)d_out + 33554432);
  float*    wxbuf = (float*)d_out;

  const dim3 gg(16, 64);  // N/128, M/128

  // Split x -> d_out, Win -> ws W-region.
  k_split_xw<<<2048, 256, 0, stream>>>(x, Win, xhi, xlo, Whi, Wlo);
  // u = silu(x . W_in^T), pre-split hi/lo f16 (pure async staging).
  k_gemm_ps<0><<<gg, 256, 0, stream>>>(xhi, xlo, Whi, Wlo, Uhi, Ulo,
                                       nullptr, nullptr, 8192, 2048, 2048);
  // Wx -> W-region (Win splits dead); init hpub/flags.
  k_convertB<<<512, 256, 0, stream>>>(Wx, h0, Whi, Wlo, hpub, flags);
  // wx[t][b][:] = u . W_x^T + b  (fp32, into d_out; x-splits dead).
  k_gemm_ps<1><<<gg, 256, 0, stream>>>(Uhi, Ulo, Whi, Wlo, nullptr, nullptr,
                                       wxbuf, bias, 8192, 2048, 2048);
  // Wout -> f16 into the dead Ulo region.
  k_convert2<<<512, 256, 0, stream>>>(Wout, WoutF);
  // sequential scan; writes outs/8 (f16) over the dead Uhi region.
  k_recur<<<128, 256, 0, stream>>>(Wh, wxbuf, h0, lal, OUTS, hpub, flags);
  // y = outs . W_out^T  (epilogue *8), overwrites d_out.
  k_gemm_out<<<gg, 256, 0, stream>>>(OUTS, WoutF, (float*)d_out, 8192, 2048, 2048);
}